// Round 14
// baseline (566.602 us; speedup 1.0000x reference)
//
#include <hip/hip_runtime.h>
#include <cstdint>
#include <cstddef>

#define B8 8
#define LSEQ 2048
#define LC 2051
#define DMODEL 1024
#define DIM 2048
#define LPAD 2054           // 3 + 2048 + 3 zero-padded rows per batch
#define M2 16408            // B8*LC valid rows
#define M2P 16512           // padded to multiple of 128
#define CS 32               // scan chunk size
#define NCH 65              // ceil(2051/32)

typedef __attribute__((ext_vector_type(8))) short short8;
typedef __attribute__((ext_vector_type(4))) float floatx4;
typedef __attribute__((ext_vector_type(2))) float float2v;

// A_n = -exp(-n/3), n=0..15
__device__ __constant__ float AeT[16] = {
  -1.0f,          -0.71653131f, -0.51341712f, -0.36787944f,
  -0.26359714f,   -0.18887560f, -0.13533528f, -0.09697208f,
  -0.06948345f,   -0.04978707f, -0.03567399f, -0.02556154f,
  -0.01831564f,   -0.01312373f, -0.00940356f, -0.00673795f};

#define LOG2E 1.44269504088896f

__device__ __forceinline__ float bf2f(unsigned short h) {
  union { unsigned int u; float f; } v; v.u = ((unsigned int)h) << 16; return v.f;
}
__device__ __forceinline__ unsigned short f2bf(float f) {
  union { float f; unsigned int u; } v; v.f = f;
  unsigned int r = (v.u + 0x7FFFu + ((v.u >> 16) & 1u)) >> 16;
  return (unsigned short)r;
}

// ---- packed fp32 helpers (VOP3P). One scalar operand allowed per instr. ----
__device__ __forceinline__ float2v pk_mul_vv(float2v a, float2v b) {
  float2v d; asm("v_pk_mul_f32 %0, %1, %2" : "=v"(d) : "v"(a), "v"(b)); return d;
}
__device__ __forceinline__ float2v pk_mul_sv(float2v bs, float2v a) {   // bs wave-uniform (SGPR)
  float2v d; asm("v_pk_mul_f32 %0, %1, %2" : "=v"(d) : "s"(bs), "v"(a)); return d;
}
__device__ __forceinline__ float2v pk_fma_vvv(float2v a, float2v b, float2v c) {
  float2v d; asm("v_pk_fma_f32 %0, %1, %2, %3" : "=v"(d) : "v"(a), "v"(b), "v"(c)); return d;
}
__device__ __forceinline__ float2v pk_fma_vsv(float2v a, float2v bs, float2v c) { // bs uniform
  float2v d; asm("v_pk_fma_f32 %0, %1, %2, %3" : "=v"(d) : "v"(a), "s"(bs), "v"(c)); return d;
}
__device__ __forceinline__ float2v pk_add_vv(float2v a, float2v b) {
  float2v d; asm("v_pk_add_f32 %0, %1, %2" : "=v"(d) : "v"(a), "v"(b)); return d;
}
__device__ __forceinline__ float exp2_raw(float x) {   // 2^x
  float d; asm("v_exp_f32 %0, %1" : "=v"(d) : "v"(x)); return d;
}

// ---------------- fused init: x->bf16, W_in/W_out/W_x->bf16, zero pads ----------------
__global__ __launch_bounds__(256) void init_kernel(const float* __restrict__ x,
                                                   const float* __restrict__ W_in,
                                                   const float* __restrict__ W_out,
                                                   const float* __restrict__ W_x,
                                                   unsigned short* __restrict__ xA,
                                                   unsigned short* __restrict__ wInB,
                                                   unsigned short* __restrict__ wOutB,
                                                   unsigned short* __restrict__ wXB,
                                                   unsigned short* __restrict__ xp) {
  const int gid = blockIdx.x;
  const float* in; unsigned short* out; int i;
  if (gid < 8192)        { in = x;     out = xA;    i = gid * 256 + threadIdx.x; }
  else if (gid < 9216)   { in = W_in;  out = wInB;  i = (gid - 8192) * 256 + threadIdx.x; }
  else if (gid < 10240)  { in = W_out; out = wOutB; i = (gid - 9216) * 256 + threadIdx.x; }
  else if (gid < 10288)  { in = W_x;   out = wXB;   i = (gid - 10240) * 256 + threadIdx.x; }
  else {
    int ii = (gid - 10288) * 256 + threadIdx.x;   // 0..12287
    int b = ii / 1536;
    int r6 = (ii % 1536) / 256;
    int dd = (ii % 256) * 8;
    int row = (r6 < 3) ? r6 : (2048 + r6);
    *(uint4*)(xp + ((size_t)b * LPAD + row) * DIM + dd) = make_uint4(0, 0, 0, 0);
    return;
  }
  const float4* p = (const float4*)in + (size_t)i * 2;
  float4 a = p[0], b = p[1];
  uint4 o;
  o.x = (unsigned)f2bf(a.x) | ((unsigned)f2bf(a.y) << 16);
  o.y = (unsigned)f2bf(a.z) | ((unsigned)f2bf(a.w) << 16);
  o.z = (unsigned)f2bf(b.x) | ((unsigned)f2bf(b.y) << 16);
  o.w = (unsigned)f2bf(b.z) | ((unsigned)f2bf(b.w) << 16);
  *((uint4*)out + i) = o;
}

// ---------------- depthwise conv1d, 16 t per block (sliding window) ----------------
__global__ __launch_bounds__(256) void conv_kernel(const unsigned short* __restrict__ xp,
                                                   const float* __restrict__ conv_w,
                                                   const float* __restrict__ conv_b,
                                                   unsigned short* __restrict__ xc) {
  const int tc0 = blockIdx.x * 16;
  const int b = blockIdx.y;
  const int d0 = threadIdx.x * 8;

  float4 cw[8];
#pragma unroll
  for (int j = 0; j < 8; ++j) cw[j] = *(const float4*)(conv_w + (size_t)(d0 + j) * 4);
  float cb[8];
  {
    const float4* cb4 = (const float4*)(conv_b + d0);
    float4 c0 = cb4[0], c1 = cb4[1];
    cb[0] = c0.x; cb[1] = c0.y; cb[2] = c0.z; cb[3] = c0.w;
    cb[4] = c1.x; cb[5] = c1.y; cb[6] = c1.z; cb[7] = c1.w;
  }

  const unsigned short* base = xp + ((size_t)b * LPAD + tc0) * DIM + d0;
  unsigned short* outp = xc + ((size_t)b * LC + tc0) * DIM + d0;

  auto loadrow = [&](float (&w)[8], int r) {
    uint4 v = *(const uint4*)(base + (size_t)r * DIM);
    w[0] = bf2f(v.x & 0xffff); w[1] = bf2f(v.x >> 16);
    w[2] = bf2f(v.y & 0xffff); w[3] = bf2f(v.y >> 16);
    w[4] = bf2f(v.z & 0xffff); w[5] = bf2f(v.z >> 16);
    w[6] = bf2f(v.w & 0xffff); w[7] = bf2f(v.w >> 16);
  };

  float wa[8], wb[8], wc[8];
  loadrow(wa, 0); loadrow(wb, 1); loadrow(wc, 2);
#pragma unroll
  for (int i = 0; i < 16; ++i) {
    float wd[8];
    loadrow(wd, i + 3);
    if (tc0 + i < LC) {
      float acc[8];
#pragma unroll
      for (int j = 0; j < 8; ++j) {
        acc[j] = cb[j];
        acc[j] = fmaf(wa[j], cw[j].x, acc[j]);
        acc[j] = fmaf(wb[j], cw[j].y, acc[j]);
        acc[j] = fmaf(wc[j], cw[j].z, acc[j]);
        acc[j] = fmaf(wd[j], cw[j].w, acc[j]);
      }
      uint4 o;
      o.x = (unsigned)f2bf(acc[0]) | ((unsigned)f2bf(acc[1]) << 16);
      o.y = (unsigned)f2bf(acc[2]) | ((unsigned)f2bf(acc[3]) << 16);
      o.z = (unsigned)f2bf(acc[4]) | ((unsigned)f2bf(acc[5]) << 16);
      o.w = (unsigned)f2bf(acc[6]) | ((unsigned)f2bf(acc[7]) << 16);
      *(uint4*)(outp + (size_t)i * DIM) = o;
    }
#pragma unroll
    for (int j = 0; j < 8; ++j) { wa[j] = wb[j]; wb[j] = wc[j]; wc[j] = wd[j]; }
  }
}

#define GAS(p) ((const __attribute__((address_space(1))) void*)(p))
#define LAS(p) ((__attribute__((address_space(3))) void*)(p))

// ---------------- bf16 MFMA GEMM, r10 known-good: BK=64, 2-barrier, 0 conflicts ----------
// 128x128 tile, 4 waves. LDS [128][64] bf16, XOR-swizzled 16B blocks: phys = log ^ (row&7),
// inverse on global staging source, forward on reads (rule #21). Measured 108-112 us, MfmaUtil 26%.
// Mapping: XCD-banded main; TAIL=1 appends extra bm row-tiles in SAME launch.
// SPLITK=1 (MODE 1): gid = bm*8+ks; each block does K/8; partials -> part[ks][r][48].
template <int MODE, int NBM, int NBN, int LX, int TAIL, int SPLITK>
__global__ __launch_bounds__(256) void gemm_bt(const unsigned short* __restrict__ A,
                                               const unsigned short* __restrict__ Bw,
                                               const float* __restrict__ bias,
                                               void* __restrict__ Cout, int K) {
  const int gid = blockIdx.x;
  const int mainBlocks = 8 * LX * NBN;
  int bm, bn, ks = 0;
  if constexpr (SPLITK) {
    ks = gid & 7;
    bm = gid >> 3;
    bn = 0;
  } else if (TAIL && gid >= mainBlocks) {
    const int e = gid - mainBlocks;
    bm = 8 * LX + e / NBN;
    bn = e % NBN;
  } else {
    const int xcd = gid & 7;
    const int j = gid >> 3;
    bm = xcd * LX + (j % LX);
    bn = j / LX;
  }
  if (bm >= NBM) return;

  __shared__ __align__(16) unsigned short As[128 * 64];   // 16KB
  __shared__ __align__(16) unsigned short Bs[128 * 64];   // 16KB
  const int tid = threadIdx.x;
  const int lane = tid & 63, wave = tid >> 6;
  const int wr = wave >> 1, wc = wave & 1;

  floatx4 acc[4][4];
#pragma unroll
  for (int i = 0; i < 4; ++i)
#pragma unroll
    for (int j2 = 0; j2 < 4; ++j2) acc[i][j2] = (floatx4){0.f, 0.f, 0.f, 0.f};

  // staging: load L covers line = L*256+tid; row = L*32 + (tid>>3), phys_blk = tid&7,
  // logical blk = phys ^ (row&7) = (tid&7)^((tid>>3)&7)  (inverse swizzle on global src).
  const int srow = tid >> 3;
  const int scol = ((tid & 7) ^ ((tid >> 3) & 7)) * 8;
  const unsigned short* Ab[4];
  const unsigned short* Bb[4];
#pragma unroll
  for (int L = 0; L < 4; ++L) {
    Ab[L] = A  + (size_t)(bm * 128 + L * 32 + srow) * K + scol;
    Bb[L] = Bw + (size_t)(bn * 128 + L * 32 + srow) * K + scol;
  }

  const int fr = lane & 15;
  const int hi = lane >> 4;
  const int fx = fr & 7;

  const int kbase = SPLITK ? ks * (K >> 3) : 0;
  const int kend = kbase + (SPLITK ? (K >> 3) : K);

  for (int k0 = kbase; k0 < kend; k0 += 64) {
    __syncthreads();  // previous compute done before overwrite
#pragma unroll
    for (int L = 0; L < 4; ++L) {
      __builtin_amdgcn_global_load_lds(GAS(Ab[L] + k0), LAS(As + L * 2048 + tid * 8), 16, 0, 0);
      __builtin_amdgcn_global_load_lds(GAS(Bb[L] + k0), LAS(Bs + L * 2048 + tid * 8), 16, 0, 0);
    }
    __syncthreads();  // drains vmcnt -> LDS ready

#pragma unroll
    for (int kk = 0; kk < 2; ++kk) {
      const int pb = ((kk * 4 + hi) ^ fx) * 8;
      short8 af[4], bf[4];
#pragma unroll
      for (int mt = 0; mt < 4; ++mt) af[mt] = *(const short8*)&As[(wr * 64 + mt * 16 + fr) * 64 + pb];
#pragma unroll
      for (int nt = 0; nt < 4; ++nt) bf[nt] = *(const short8*)&Bs[(wc * 64 + nt * 16 + fr) * 64 + pb];
#pragma unroll
      for (int mt = 0; mt < 4; ++mt)
#pragma unroll
        for (int nt = 0; nt < 4; ++nt)
          acc[mt][nt] = __builtin_amdgcn_mfma_f32_16x16x32_bf16(af[mt], bf[nt], acc[mt][nt], 0, 0, 0);
    }
  }

  const int er = (lane >> 4) * 4, ec = lane & 15;
#pragma unroll
  for (int mt = 0; mt < 4; ++mt) {
#pragma unroll
    for (int nt = 0; nt < 4; ++nt) {
#pragma unroll
      for (int i = 0; i < 4; ++i) {
        int r = bm * 128 + wr * 64 + mt * 16 + er + i;
        int c = bn * 128 + wc * 64 + nt * 16 + ec;
        float v = acc[mt][nt][i];
        if constexpr (MODE == 0) {
          int bb = r >> 11, t = r & 2047;
          ((unsigned short*)Cout)[((size_t)bb * LPAD + 3 + t) * DIM + c] = f2bf(v + bias[c]);
        } else if constexpr (MODE == 1) {
          if (c < 48) ((float*)Cout)[((size_t)ks * M2P + r) * 48 + c] = v;
        } else {
          if (r < M2) ((float*)Cout)[(size_t)r * DMODEL + c] = v + bias[c];
        }
      }
    }
  }
}

// ---------------- reduce split-K partials -> xdbl (deterministic, no atomics) ----------
__global__ __launch_bounds__(256) void reduce_xdbl(const float* __restrict__ part,
                                                   float* __restrict__ xdbl) {
  int i = blockIdx.x * 256 + threadIdx.x;     // float4 index over [M2][48]
  if (i >= 196896) return;                    // 16408*48/4
  float4 s = make_float4(0.f, 0.f, 0.f, 0.f);
#pragma unroll
  for (int ks = 0; ks < 8; ++ks) {
    float4 v = *(const float4*)(part + (size_t)ks * M2P * 48 + (size_t)i * 4);
    s.x += v.x; s.y += v.y; s.z += v.z; s.w += v.w;
  }
  *(float4*)(xdbl + (size_t)i * 4) = s;
}

// ---------------- chunked scan, pass 1: fused softplus-delta; per-chunk (sumd, q) ------
// delta computed in-register: z = b_dt[d] + sum_n d_raw[n]*W_dt[d][n] with d_raw wave-uniform
// (SGPR via s_load) -> 8 pk_fma; softplus = log(1+exp(z)). Removes the delta buffer and its
// 2x64MB re-reads. Fixed-association source => identical value in pass1/pass2.
__global__ __launch_bounds__(256) void scan_pass1(const unsigned short* __restrict__ xc,
                                                  const float* __restrict__ xd,
                                                  const float* __restrict__ W_dt,
                                                  const float* __restrict__ b_dt,
                                                  unsigned short* __restrict__ sdbuf,
                                                  unsigned short* __restrict__ qbuf) {
  const int wid = __builtin_amdgcn_readfirstlane((int)(threadIdx.x >> 6));
  const int lane = threadIdx.x & 63;
  const int W = blockIdx.x * 4 + wid;
  const int dg = W & 31;
  const int rest = W >> 5;
  const int c = rest % NCH;
  const int b = rest / NCH;
  const int d = dg * 64 + lane;
  const int t0 = c * CS;
  const int nst = (t0 + CS <= LC) ? CS : (LC - t0);

  float2v A2L[8];
#pragma unroll
  for (int i = 0; i < 8; ++i)
    A2L[i] = (float2v){AeT[2 * i] * LOG2E, AeT[2 * i + 1] * LOG2E};

  float2v wdt2[8];
  {
    const float4* wp = (const float4*)(W_dt + (size_t)d * 16);
#pragma unroll
    for (int q = 0; q < 4; ++q) {
      float4 t = wp[q];
      wdt2[q * 2 + 0] = (float2v){t.x, t.y};
      wdt2[q * 2 + 1] = (float2v){t.z, t.w};
    }
  }
  const float bd = b_dt[d];

  float2v h2[8];
#pragma unroll
  for (int i = 0; i < 8; ++i) h2[i] = (float2v){0.f, 0.f};
  float sumd = 0.f;

  const size_t row0 = (size_t)b * LC + t0;
  const float* xdb = xd + row0 * 48;                 // d_raw 0..15, B 16..31 (uniform -> s_load)
  const unsigned short* xcp = xc + row0 * DIM + d;

  auto body = [&](int s) {
    const float* xr = xdb + (size_t)s * 48;
    float2v z2[4];
#pragma unroll
    for (int i = 0; i < 4; ++i) z2[i] = (float2v){0.f, 0.f};
#pragma unroll
    for (int i = 0; i < 8; ++i)
      z2[i & 3] = pk_fma_vsv(wdt2[i], *(const float2v*)(xr + 2 * i), z2[i & 3]);
    float2v zt = pk_add_vv(pk_add_vv(z2[0], z2[1]), pk_add_vv(z2[2], z2[3]));
    float z = bd + zt.x + zt.y;
    float dlt = (z > 20.f) ? z : __logf(1.f + __expf(z));
    float xcv = bf2f(xcp[(size_t)s * DIM]);
    sumd += dlt;
    float2v dlt2 = (float2v){dlt, dlt};
    float2v xcv2 = (float2v){xcv, xcv};
#pragma unroll
    for (int i = 0; i < 8; ++i) {
      float2v arg = pk_mul_vv(dlt2, A2L[i]);
      float e0 = exp2_raw(arg.x), e1 = exp2_raw(arg.y);
      float2v e2 = (float2v){e0, e1};
      h2[i] = pk_fma_vvv(h2[i], e2, pk_mul_sv(*(const float2v*)(xr + 16 + 2 * i), xcv2));
    }
  };

  if (nst == CS) {
#pragma unroll
    for (int s = 0; s < CS; ++s) body(s);
  } else {
    for (int s = 0; s < nst; ++s) body(s);
  }

  sdbuf[((size_t)(b * NCH + c) << 11) + d] = f2bf(sumd);
  const size_t base = ((size_t)(b * NCH + c) * 16) * 2048 + d;
#pragma unroll
  for (int i = 0; i < 8; ++i) {
    qbuf[base + ((size_t)(2 * i) << 11)]     = f2bf(h2[i].x);
    qbuf[base + ((size_t)(2 * i + 1) << 11)] = f2bf(h2[i].y);
  }
}

// ---------------- boundary scan: 1 lane per (b,d,n); h across chunks, h_init over q ----
__global__ __launch_bounds__(256) void scan_boundary(const unsigned short* __restrict__ sdbuf,
                                                     unsigned short* __restrict__ qbuf) {
  const int tid = threadIdx.x;
  const int n = tid >> 4;
  const int d = blockIdx.x * 16 + (tid & 15);
  const int b = blockIdx.y;
  const float aL = AeT[n] * LOG2E;
  float h = 0.f;
  for (int c = 0; c < NCH; ++c) {
    const size_t sbase = ((size_t)(b * NCH + c) << 11);
    const float sd = bf2f(sdbuf[sbase + d]);
    const size_t base = (sbase << 4) + ((size_t)n << 11) + d;
    const float qv = bf2f(qbuf[base]);
    const float Pv = exp2_raw(sd * aL);
    qbuf[base] = f2bf(h);
    h = fmaf(Pv, h, qv);
  }
}

// ---------------- chunked scan, pass 2: fused delta; recompute with h_init, emit y -----
__global__ __launch_bounds__(256) void scan_pass2(const unsigned short* __restrict__ xc,
                                                  const float* __restrict__ xd,
                                                  const float* __restrict__ W_dt,
                                                  const float* __restrict__ b_dt,
                                                  const unsigned short* __restrict__ hinit,
                                                  unsigned short* __restrict__ y) {
  const int wid = __builtin_amdgcn_readfirstlane((int)(threadIdx.x >> 6));
  const int lane = threadIdx.x & 63;
  const int W = blockIdx.x * 4 + wid;
  const int dg = W & 31;
  const int rest = W >> 5;
  const int c = rest % NCH;
  const int b = rest / NCH;
  const int d = dg * 64 + lane;
  const int t0 = c * CS;
  const int nst = (t0 + CS <= LC) ? CS : (LC - t0);

  float2v A2L[8];
#pragma unroll
  for (int i = 0; i < 8; ++i)
    A2L[i] = (float2v){AeT[2 * i] * LOG2E, AeT[2 * i + 1] * LOG2E};

  float2v wdt2[8];
  {
    const float4* wp = (const float4*)(W_dt + (size_t)d * 16);
#pragma unroll
    for (int q = 0; q < 4; ++q) {
      float4 t = wp[q];
      wdt2[q * 2 + 0] = (float2v){t.x, t.y};
      wdt2[q * 2 + 1] = (float2v){t.z, t.w};
    }
  }
  const float bd = b_dt[d];

  const size_t base = ((size_t)(b * NCH + c) * 16) * 2048 + d;
  float2v h2[8];
#pragma unroll
  for (int i = 0; i < 8; ++i)
    h2[i] = (float2v){bf2f(hinit[base + ((size_t)(2 * i) << 11)]),
                      bf2f(hinit[base + ((size_t)(2 * i + 1) << 11)])};

  const size_t row0 = (size_t)b * LC + t0;
  const float* xdb = xd + row0 * 48;                 // d_raw 0..15, B 16..31, C 32..47
  const unsigned short* xcp = xc + row0 * DIM + d;
  unsigned short* yp = y + row0 * DIM + d;

  auto body = [&](int s) {
    const float* xr = xdb + (size_t)s * 48;
    float2v z2[4];
#pragma unroll
    for (int i = 0; i < 4; ++i) z2[i] = (float2v){0.f, 0.f};
#pragma unroll
    for (int i = 0; i < 8; ++i)
      z2[i & 3] = pk_fma_vsv(wdt2[i], *(const float2v*)(xr + 2 * i), z2[i & 3]);
    float2v zt = pk_add_vv(pk_add_vv(z2[0], z2[1]), pk_add_vv(z2[2], z2[3]));
    float z = bd + zt.x + zt.y;
    float dlt = (z > 20.f) ? z : __logf(1.f + __expf(z));
    float xcv = bf2f(xcp[(size_t)s * DIM]);
    float2v dlt2 = (float2v){dlt, dlt};
    float2v xcv2 = (float2v){xcv, xcv};
    float2v y2[4];
#pragma unroll
    for (int i = 0; i < 4; ++i) y2[i] = (float2v){0.f, 0.f};
#pragma unroll
    for (int i = 0; i < 8; ++i) {
      float2v arg = pk_mul_vv(dlt2, A2L[i]);
      float e0 = exp2_raw(arg.x), e1 = exp2_raw(arg.y);
      float2v e2 = (float2v){e0, e1};
      h2[i] = pk_fma_vvv(h2[i], e2, pk_mul_sv(*(const float2v*)(xr + 16 + 2 * i), xcv2));
      y2[i & 3] = pk_fma_vsv(h2[i], *(const float2v*)(xr + 32 + 2 * i), y2[i & 3]);
    }
    float2v s01 = pk_add_vv(y2[0], y2[1]);
    float2v s23 = pk_add_vv(y2[2], y2[3]);
    float2v st = pk_add_vv(s01, s23);
    yp[(size_t)s * DIM] = f2bf(st.x + st.y);
  };

  if (nst == CS) {
#pragma unroll
    for (int s = 0; s < CS; ++s) body(s);
  } else {
    for (int s = 0; s < nst; ++s) body(s);
  }
}

// ---------------- launch ----------------
extern "C" void kernel_launch(void* const* d_in, const int* in_sizes, int n_in,
                              void* d_out, int out_size, void* d_ws, size_t ws_size,
                              hipStream_t stream) {
  const float* x      = (const float*)d_in[0];
  const float* W_in   = (const float*)d_in[1];
  const float* b_in   = (const float*)d_in[2];
  const float* conv_w = (const float*)d_in[3];
  const float* conv_b = (const float*)d_in[4];
  const float* W_x    = (const float*)d_in[5];
  const float* W_dt   = (const float*)d_in[6];
  const float* b_dt   = (const float*)d_in[7];
  const float* W_out  = (const float*)d_in[8];
  const float* b_out  = (const float*)d_in[9];

  char* w = (char*)d_ws;
  // region 0 (67.63 MB): xp (LPAD layout, dead after conv) -> ybuf [M2P][DIM] bf16
  unsigned short* xp    = (unsigned short*)w;
  unsigned short* ybuf  = (unsigned short*)w;
  size_t off = (size_t)M2P * DIM * 2;                                  // 67,633,152
  unsigned short* xcb  = (unsigned short*)(w + off); off += (size_t)M2P * DIM * 2;
  size_t xA_off = off;                                                 // 135,266,304
  unsigned short* xA   = (unsigned short*)(w + off); off += (size_t)16384 * 1024 * 2;
  unsigned short* wInB = (unsigned short*)(w + off); off += (size_t)2048 * 1024 * 2;
  unsigned short* wOutB= (unsigned short*)(w + off); off += (size_t)1024 * 2048 * 2;
  unsigned short* wXB  = (unsigned short*)(w + off); off += (size_t)128 * 2048 * 2;
  float* xdbl          = (float*)(w + off);          off += (size_t)M2 * 48 * 4;
  // xA region (37.5 MB, dead after gemm<0>) reused twice:
  //  1) split-K partials (8 * M2P * 48 * 4 = 25.4 MB) between gemm<1> and reduce
  //  2) sdbuf (2.13 MB) + qbuf (34.08 MB) bf16 from scan_pass1 onward
  float* part           = (float*)(w + xA_off);
  unsigned short* sdbuf = (unsigned short*)(w + xA_off);
  unsigned short* qbuf  = (unsigned short*)(w + xA_off + (size_t)B8 * NCH * 2048 * 2);
  (void)ws_size; (void)in_sizes; (void)n_in; (void)out_size;

  init_kernel<<<10336, 256, 0, stream>>>(x, W_in, W_out, W_x, xA, wInB, wOutB, wXB, xp);

  // gemm<0>: 128 bm tiles exact (8 blocks/CU)
  gemm_bt<0, 128, 16, 16, 0, 0><<<2048, 256, 0, stream>>>(xA, wInB, b_in, xp, 1024);
  conv_kernel<<<dim3(129, B8), 256, 0, stream>>>(xp, conv_w, conv_b, xcb);
  // gemm<1>: split-K=8, partials -> part, deterministic reduce
  gemm_bt<1, 129, 1, 0, 0, 1><<<1032, 256, 0, stream>>>(xcb, wXB, nullptr, part, 2048);
  reduce_xdbl<<<770, 256, 0, stream>>>(part, xdbl);

  scan_pass1<<<4160, 256, 0, stream>>>(xcb, xdbl, W_dt, b_dt, sdbuf, qbuf);
  scan_boundary<<<dim3(128, B8), 256, 0, stream>>>(sdbuf, qbuf);
  scan_pass2<<<4160, 256, 0, stream>>>(xcb, xdbl, W_dt, b_dt, qbuf, ybuf);

  // gemm<2>: banded 1024 + 8 integrated tail blocks (bm=128, bn=0..7)
  gemm_bt<2, 129, 8, 16, 1, 0><<<1032, 256, 0, stream>>>(ybuf, wOutB, b_out, (float*)d_out, 2048);
}

// Round 15
// 518.704 us; speedup vs baseline: 1.0923x; 1.0923x over previous
//
#include <hip/hip_runtime.h>
#include <cstdint>
#include <cstddef>

#define B8 8
#define LSEQ 2048
#define LC 2051
#define DMODEL 1024
#define DIM 2048
#define LPAD 2054           // 3 + 2048 + 3 zero-padded rows per batch
#define M2 16408            // B8*LC valid rows
#define M2P 16512           // padded to multiple of 128
#define CS 32               // scan chunk size
#define NCH 65              // ceil(2051/32)

typedef __attribute__((ext_vector_type(8))) short short8;
typedef __attribute__((ext_vector_type(4))) float floatx4;
typedef __attribute__((ext_vector_type(2))) float float2v;

// A_n = -exp(-n/3), n=0..15
__device__ __constant__ float AeT[16] = {
  -1.0f,          -0.71653131f, -0.51341712f, -0.36787944f,
  -0.26359714f,   -0.18887560f, -0.13533528f, -0.09697208f,
  -0.06948345f,   -0.04978707f, -0.03567399f, -0.02556154f,
  -0.01831564f,   -0.01312373f, -0.00940356f, -0.00673795f};

#define LOG2E 1.44269504088896f

__device__ __forceinline__ float bf2f(unsigned short h) {
  union { unsigned int u; float f; } v; v.u = ((unsigned int)h) << 16; return v.f;
}
__device__ __forceinline__ unsigned short f2bf(float f) {
  union { float f; unsigned int u; } v; v.f = f;
  unsigned int r = (v.u + 0x7FFFu + ((v.u >> 16) & 1u)) >> 16;
  return (unsigned short)r;
}

// ---- packed fp32 helpers (VOP3P). One scalar operand allowed per instr. ----
__device__ __forceinline__ float2v pk_mul_vv(float2v a, float2v b) {
  float2v d; asm("v_pk_mul_f32 %0, %1, %2" : "=v"(d) : "v"(a), "v"(b)); return d;
}
__device__ __forceinline__ float2v pk_mul_sv(float2v bs, float2v a) {   // bs wave-uniform (SGPR)
  float2v d; asm("v_pk_mul_f32 %0, %1, %2" : "=v"(d) : "s"(bs), "v"(a)); return d;
}
__device__ __forceinline__ float2v pk_fma_vvv(float2v a, float2v b, float2v c) {
  float2v d; asm("v_pk_fma_f32 %0, %1, %2, %3" : "=v"(d) : "v"(a), "v"(b), "v"(c)); return d;
}
__device__ __forceinline__ float2v pk_fma_vsv(float2v a, float2v bs, float2v c) { // bs uniform
  float2v d; asm("v_pk_fma_f32 %0, %1, %2, %3" : "=v"(d) : "v"(a), "s"(bs), "v"(c)); return d;
}
__device__ __forceinline__ float2v pk_add_vv(float2v a, float2v b) {
  float2v d; asm("v_pk_add_f32 %0, %1, %2" : "=v"(d) : "v"(a), "v"(b)); return d;
}
__device__ __forceinline__ float exp2_raw(float x) {   // 2^x
  float d; asm("v_exp_f32 %0, %1" : "=v"(d) : "v"(x)); return d;
}

// ---- opaque LDS read: prevents compiler-inserted vmcnt(0) before ds_read ----
typedef __attribute__((address_space(3))) unsigned short lds_ushort;
__device__ __forceinline__ short8 ds_read_b128_(const lds_ushort* p) {
  floatx4 d;
  unsigned addr = (unsigned)(size_t)p;
  asm volatile("ds_read_b128 %0, %1" : "=v"(d) : "v"(addr));
  return __builtin_bit_cast(short8, d);
}

// ---------------- fused init: x->bf16, W_in/W_out/W_x->bf16, zero pads ----------------
__global__ __launch_bounds__(256) void init_kernel(const float* __restrict__ x,
                                                   const float* __restrict__ W_in,
                                                   const float* __restrict__ W_out,
                                                   const float* __restrict__ W_x,
                                                   unsigned short* __restrict__ xA,
                                                   unsigned short* __restrict__ wInB,
                                                   unsigned short* __restrict__ wOutB,
                                                   unsigned short* __restrict__ wXB,
                                                   unsigned short* __restrict__ xp) {
  const int gid = blockIdx.x;
  const float* in; unsigned short* out; int i;
  if (gid < 8192)        { in = x;     out = xA;    i = gid * 256 + threadIdx.x; }
  else if (gid < 9216)   { in = W_in;  out = wInB;  i = (gid - 8192) * 256 + threadIdx.x; }
  else if (gid < 10240)  { in = W_out; out = wOutB; i = (gid - 9216) * 256 + threadIdx.x; }
  else if (gid < 10288)  { in = W_x;   out = wXB;   i = (gid - 10240) * 256 + threadIdx.x; }
  else {
    int ii = (gid - 10288) * 256 + threadIdx.x;   // 0..12287
    int b = ii / 1536;
    int r6 = (ii % 1536) / 256;
    int dd = (ii % 256) * 8;
    int row = (r6 < 3) ? r6 : (2048 + r6);
    *(uint4*)(xp + ((size_t)b * LPAD + row) * DIM + dd) = make_uint4(0, 0, 0, 0);
    return;
  }
  const float4* p = (const float4*)in + (size_t)i * 2;
  float4 a = p[0], b = p[1];
  uint4 o;
  o.x = (unsigned)f2bf(a.x) | ((unsigned)f2bf(a.y) << 16);
  o.y = (unsigned)f2bf(a.z) | ((unsigned)f2bf(a.w) << 16);
  o.z = (unsigned)f2bf(b.x) | ((unsigned)f2bf(b.y) << 16);
  o.w = (unsigned)f2bf(b.z) | ((unsigned)f2bf(b.w) << 16);
  *((uint4*)out + i) = o;
}

// ---------------- depthwise conv1d, 16 t per block (sliding window) ----------------
__global__ __launch_bounds__(256) void conv_kernel(const unsigned short* __restrict__ xp,
                                                   const float* __restrict__ conv_w,
                                                   const float* __restrict__ conv_b,
                                                   unsigned short* __restrict__ xc) {
  const int tc0 = blockIdx.x * 16;
  const int b = blockIdx.y;
  const int d0 = threadIdx.x * 8;

  float4 cw[8];
#pragma unroll
  for (int j = 0; j < 8; ++j) cw[j] = *(const float4*)(conv_w + (size_t)(d0 + j) * 4);
  float cb[8];
  {
    const float4* cb4 = (const float4*)(conv_b + d0);
    float4 c0 = cb4[0], c1 = cb4[1];
    cb[0] = c0.x; cb[1] = c0.y; cb[2] = c0.z; cb[3] = c0.w;
    cb[4] = c1.x; cb[5] = c1.y; cb[6] = c1.z; cb[7] = c1.w;
  }

  const unsigned short* base = xp + ((size_t)b * LPAD + tc0) * DIM + d0;
  unsigned short* outp = xc + ((size_t)b * LC + tc0) * DIM + d0;

  auto loadrow = [&](float (&w)[8], int r) {
    uint4 v = *(const uint4*)(base + (size_t)r * DIM);
    w[0] = bf2f(v.x & 0xffff); w[1] = bf2f(v.x >> 16);
    w[2] = bf2f(v.y & 0xffff); w[3] = bf2f(v.y >> 16);
    w[4] = bf2f(v.z & 0xffff); w[5] = bf2f(v.z >> 16);
    w[6] = bf2f(v.w & 0xffff); w[7] = bf2f(v.w >> 16);
  };

  float wa[8], wb[8], wc[8];
  loadrow(wa, 0); loadrow(wb, 1); loadrow(wc, 2);
#pragma unroll
  for (int i = 0; i < 16; ++i) {
    float wd[8];
    loadrow(wd, i + 3);
    if (tc0 + i < LC) {
      float acc[8];
#pragma unroll
      for (int j = 0; j < 8; ++j) {
        acc[j] = cb[j];
        acc[j] = fmaf(wa[j], cw[j].x, acc[j]);
        acc[j] = fmaf(wb[j], cw[j].y, acc[j]);
        acc[j] = fmaf(wc[j], cw[j].z, acc[j]);
        acc[j] = fmaf(wd[j], cw[j].w, acc[j]);
      }
      uint4 o;
      o.x = (unsigned)f2bf(acc[0]) | ((unsigned)f2bf(acc[1]) << 16);
      o.y = (unsigned)f2bf(acc[2]) | ((unsigned)f2bf(acc[3]) << 16);
      o.z = (unsigned)f2bf(acc[4]) | ((unsigned)f2bf(acc[5]) << 16);
      o.w = (unsigned)f2bf(acc[6]) | ((unsigned)f2bf(acc[7]) << 16);
      *(uint4*)(outp + (size_t)i * DIM) = o;
    }
#pragma unroll
    for (int j = 0; j < 8; ++j) { wa[j] = wb[j]; wb[j] = wc[j]; wc[j] = wd[j]; }
  }
}

#define GAS(p) ((const __attribute__((address_space(1))) void*)(p))
#define LAS(p) ((__attribute__((address_space(3))) void*)(p))

// ---------------- bf16 MFMA GEMM, known-good: BK=64, 2-barrier, 0 conflicts ----------
// 128x128 tile, 4 waves. LDS [128][64] bf16, XOR-swizzled 16B blocks: phys = log ^ (row&7),
// inverse on global staging source, forward on reads (rule #21). 108-112 us, MfmaUtil 26%.
// Mapping: XCD-banded main; TAIL=1 appends extra bm row-tiles in SAME launch.
// SPLITK=1 (MODE 1): gid = bm*8+ks; each block does K/8; partials -> part[ks][r][48].
template <int MODE, int NBM, int NBN, int LX, int TAIL, int SPLITK>
__global__ __launch_bounds__(256) void gemm_bt(const unsigned short* __restrict__ A,
                                               const unsigned short* __restrict__ Bw,
                                               const float* __restrict__ bias,
                                               void* __restrict__ Cout, int K) {
  const int gid = blockIdx.x;
  const int mainBlocks = 8 * LX * NBN;
  int bm, bn, ks = 0;
  if constexpr (SPLITK) {
    ks = gid & 7;
    bm = gid >> 3;
    bn = 0;
  } else if (TAIL && gid >= mainBlocks) {
    const int e = gid - mainBlocks;
    bm = 8 * LX + e / NBN;
    bn = e % NBN;
  } else {
    const int xcd = gid & 7;
    const int j = gid >> 3;
    bm = xcd * LX + (j % LX);
    bn = j / LX;
  }
  if (bm >= NBM) return;

  __shared__ __align__(16) unsigned short As[128 * 64];   // 16KB
  __shared__ __align__(16) unsigned short Bs[128 * 64];   // 16KB
  const int tid = threadIdx.x;
  const int lane = tid & 63, wave = tid >> 6;
  const int wr = wave >> 1, wc = wave & 1;

  floatx4 acc[4][4];
#pragma unroll
  for (int i = 0; i < 4; ++i)
#pragma unroll
    for (int j2 = 0; j2 < 4; ++j2) acc[i][j2] = (floatx4){0.f, 0.f, 0.f, 0.f};

  // staging: load L covers line = L*256+tid; row = L*32 + (tid>>3), phys_blk = tid&7,
  // logical blk = phys ^ (row&7) = (tid&7)^((tid>>3)&7)  (inverse swizzle on global src).
  const int srow = tid >> 3;
  const int scol = ((tid & 7) ^ ((tid >> 3) & 7)) * 8;
  const unsigned short* Ab[4];
  const unsigned short* Bb[4];
#pragma unroll
  for (int L = 0; L < 4; ++L) {
    Ab[L] = A  + (size_t)(bm * 128 + L * 32 + srow) * K + scol;
    Bb[L] = Bw + (size_t)(bn * 128 + L * 32 + srow) * K + scol;
  }

  const int fr = lane & 15;
  const int hi = lane >> 4;
  const int fx = fr & 7;

  const int kbase = SPLITK ? ks * (K >> 3) : 0;
  const int kend = kbase + (SPLITK ? (K >> 3) : K);

  for (int k0 = kbase; k0 < kend; k0 += 64) {
    __syncthreads();  // previous compute done before overwrite
#pragma unroll
    for (int L = 0; L < 4; ++L) {
      __builtin_amdgcn_global_load_lds(GAS(Ab[L] + k0), LAS(As + L * 2048 + tid * 8), 16, 0, 0);
      __builtin_amdgcn_global_load_lds(GAS(Bb[L] + k0), LAS(Bs + L * 2048 + tid * 8), 16, 0, 0);
    }
    __syncthreads();  // drains vmcnt -> LDS ready

#pragma unroll
    for (int kk = 0; kk < 2; ++kk) {
      const int pb = ((kk * 4 + hi) ^ fx) * 8;
      short8 af[4], bf[4];
#pragma unroll
      for (int mt = 0; mt < 4; ++mt) af[mt] = *(const short8*)&As[(wr * 64 + mt * 16 + fr) * 64 + pb];
#pragma unroll
      for (int nt = 0; nt < 4; ++nt) bf[nt] = *(const short8*)&Bs[(wc * 64 + nt * 16 + fr) * 64 + pb];
#pragma unroll
      for (int mt = 0; mt < 4; ++mt)
#pragma unroll
        for (int nt = 0; nt < 4; ++nt)
          acc[mt][nt] = __builtin_amdgcn_mfma_f32_16x16x32_bf16(af[mt], bf[nt], acc[mt][nt], 0, 0, 0);
    }
  }

  const int er = (lane >> 4) * 4, ec = lane & 15;
#pragma unroll
  for (int mt = 0; mt < 4; ++mt) {
#pragma unroll
    for (int nt = 0; nt < 4; ++nt) {
#pragma unroll
      for (int i = 0; i < 4; ++i) {
        int r = bm * 128 + wr * 64 + mt * 16 + er + i;
        int c = bn * 128 + wc * 64 + nt * 16 + ec;
        float v = acc[mt][nt][i];
        if constexpr (MODE == 0) {
          int bb = r >> 11, t = r & 2047;
          ((unsigned short*)Cout)[((size_t)bb * LPAD + 3 + t) * DIM + c] = f2bf(v + bias[c]);
        } else if constexpr (MODE == 1) {
          if (c < 48) ((float*)Cout)[((size_t)ks * M2P + r) * 48 + c] = v;
        } else {
          if (r < M2) ((float*)Cout)[(size_t)r * DMODEL + c] = v + bias[c];
        }
      }
    }
  }
}

// ---------------- reduce split-K partials -> xdbl (deterministic, no atomics) ----------
__global__ __launch_bounds__(256) void reduce_xdbl(const float* __restrict__ part,
                                                   float* __restrict__ xdbl) {
  int i = blockIdx.x * 256 + threadIdx.x;     // float4 index over [M2][48]
  if (i >= 196896) return;                    // 16408*48/4
  float4 s = make_float4(0.f, 0.f, 0.f, 0.f);
#pragma unroll
  for (int ks = 0; ks < 8; ++ks) {
    float4 v = *(const float4*)(part + (size_t)ks * M2P * 48 + (size_t)i * 4);
    s.x += v.x; s.y += v.y; s.z += v.z; s.w += v.w;
  }
  *(float4*)(xdbl + (size_t)i * 4) = s;
}

// ---------------- delta precompute: softplus(d_raw @ W_dt.T + b_dt) -> bf16 ----------------
__global__ __launch_bounds__(256) void delta_kernel(const float* __restrict__ xdbl,
                                                    const float* __restrict__ W_dt,
                                                    const float* __restrict__ b_dt,
                                                    unsigned short* __restrict__ delta) {
  const int d = blockIdx.y * 256 + threadIdx.x;
  const int r0 = blockIdx.x * 8;
  float wv[16];
  const float4* wp = (const float4*)(W_dt + (size_t)d * 16);
#pragma unroll
  for (int q = 0; q < 4; ++q) {
    float4 t = wp[q];
    wv[q * 4 + 0] = t.x; wv[q * 4 + 1] = t.y; wv[q * 4 + 2] = t.z; wv[q * 4 + 3] = t.w;
  }
  const float bd = b_dt[d];
#pragma unroll
  for (int j = 0; j < 8; ++j) {
    const float* dr = xdbl + (size_t)(r0 + j) * 48;   // uniform -> s_load
    float z0 = bd, z1 = 0.f, z2 = 0.f, z3 = 0.f;
#pragma unroll
    for (int n = 0; n < 16; n += 4) {
      z0 = fmaf(dr[n + 0], wv[n + 0], z0);
      z1 = fmaf(dr[n + 1], wv[n + 1], z1);
      z2 = fmaf(dr[n + 2], wv[n + 2], z2);
      z3 = fmaf(dr[n + 3], wv[n + 3], z3);
    }
    float z = (z0 + z1) + (z2 + z3);
    float dl = (z > 20.f) ? z : __logf(1.f + __expf(z));
    delta[(size_t)(r0 + j) * DIM + d] = f2bf(dl);
  }
}

// ---------------- chunked scan, pass 1: per-chunk (sumd, q) -> bf16 ----------------
__global__ __launch_bounds__(256) void scan_pass1(const unsigned short* __restrict__ xc,
                                                  const unsigned short* __restrict__ dl,
                                                  const float* __restrict__ xd,
                                                  unsigned short* __restrict__ sdbuf,
                                                  unsigned short* __restrict__ qbuf) {
  const int wid = __builtin_amdgcn_readfirstlane((int)(threadIdx.x >> 6));
  const int lane = threadIdx.x & 63;
  const int W = blockIdx.x * 4 + wid;
  const int dg = W & 31;
  const int rest = W >> 5;
  const int c = rest % NCH;
  const int b = rest / NCH;
  const int d = dg * 64 + lane;
  const int t0 = c * CS;
  const int nst = (t0 + CS <= LC) ? CS : (LC - t0);

  float2v A2L[8];
#pragma unroll
  for (int i = 0; i < 8; ++i)
    A2L[i] = (float2v){AeT[2 * i] * LOG2E, AeT[2 * i + 1] * LOG2E};

  float2v h2[8];
#pragma unroll
  for (int i = 0; i < 8; ++i) h2[i] = (float2v){0.f, 0.f};
  float sumd = 0.f;

  const size_t row0 = (size_t)b * LC + t0;
  const float* xdb = xd + row0 * 48 + 16;            // B cols (uniform -> s_load)
  const unsigned short* xcp = xc + row0 * DIM + d;
  const unsigned short* dp  = dl + row0 * DIM + d;

  auto body = [&](int s) {
    float2v Bv[8];
#pragma unroll
    for (int j = 0; j < 8; ++j) Bv[j] = *(const float2v*)(xdb + (size_t)s * 48 + 2 * j);
    float dlt = bf2f(dp[(size_t)s * DIM]);
    float xcv = bf2f(xcp[(size_t)s * DIM]);
    sumd += dlt;
    float2v dlt2 = (float2v){dlt, dlt};
    float2v xcv2 = (float2v){xcv, xcv};
#pragma unroll
    for (int i = 0; i < 8; ++i) {
      float2v arg = pk_mul_vv(dlt2, A2L[i]);
      float e0 = exp2_raw(arg.x), e1 = exp2_raw(arg.y);
      float2v e2 = (float2v){e0, e1};
      h2[i] = pk_fma_vvv(h2[i], e2, pk_mul_sv(Bv[i], xcv2));
    }
  };

  if (nst == CS) {
#pragma unroll
    for (int s = 0; s < CS; ++s) body(s);
  } else {
    for (int s = 0; s < nst; ++s) body(s);
  }

  sdbuf[((size_t)(b * NCH + c) << 11) + d] = f2bf(sumd);
  const size_t base = ((size_t)(b * NCH + c) * 16) * 2048 + d;
#pragma unroll
  for (int i = 0; i < 8; ++i) {
    qbuf[base + ((size_t)(2 * i) << 11)]     = f2bf(h2[i].x);
    qbuf[base + ((size_t)(2 * i + 1) << 11)] = f2bf(h2[i].y);
  }
}

// ---------------- boundary scan: 1 lane per (b,d,n); h across chunks, h_init over q ----
__global__ __launch_bounds__(256) void scan_boundary(const unsigned short* __restrict__ sdbuf,
                                                     unsigned short* __restrict__ qbuf) {
  const int tid = threadIdx.x;
  const int n = tid >> 4;
  const int d = blockIdx.x * 16 + (tid & 15);
  const int b = blockIdx.y;
  const float aL = AeT[n] * LOG2E;
  float h = 0.f;
  for (int c = 0; c < NCH; ++c) {
    const size_t sbase = ((size_t)(b * NCH + c) << 11);
    const float sd = bf2f(sdbuf[sbase + d]);
    const size_t base = (sbase << 4) + ((size_t)n << 11) + d;
    const float qv = bf2f(qbuf[base]);
    const float Pv = exp2_raw(sd * aL);
    qbuf[base] = f2bf(h);
    h = fmaf(Pv, h, qv);
  }
}

// ---------------- chunked scan, pass 2: recompute with h_init, emit y ----------------
// NOTE: y aliases dl (in-place, same [r][d] layout); only the owning thread touches
// each element and reads precede the store for that row.
__global__ __launch_bounds__(256) void scan_pass2(const unsigned short* __restrict__ xc,
                                                  const unsigned short* __restrict__ dl,
                                                  const float* __restrict__ xd,
                                                  const unsigned short* __restrict__ hinit,
                                                  unsigned short* __restrict__ y) {
  const int wid = __builtin_amdgcn_readfirstlane((int)(threadIdx.x >> 6));
  const int lane = threadIdx.x & 63;
  const int W = blockIdx.x * 4 + wid;
  const int dg = W & 31;
  const int rest = W >> 5;
  const int c = rest % NCH;
  const int b = rest / NCH;
  const int d = dg * 64 + lane;
  const int t0 = c * CS;
  const int nst = (t0 + CS <= LC) ? CS : (LC - t0);

  float2v A2L[8];
#pragma unroll
  for (int i = 0; i < 8; ++i)
    A2L[i] = (float2v){AeT[2 * i] * LOG2E, AeT[2 * i + 1] * LOG2E};

  const size_t base = ((size_t)(b * NCH + c) * 16) * 2048 + d;
  float2v h2[8];
#pragma unroll
  for (int i = 0; i < 8; ++i)
    h2[i] = (float2v){bf2f(hinit[base + ((size_t)(2 * i) << 11)]),
                      bf2f(hinit[base + ((size_t)(2 * i + 1) << 11)])};

  const size_t row0 = (size_t)b * LC + t0;
  const float* xdb = xd + row0 * 48 + 16;            // B at [j], C at [16+j]
  const unsigned short* xcp = xc + row0 * DIM + d;
  const unsigned short* dp  = dl + row0 * DIM + d;
  unsigned short* yp = y + row0 * DIM + d;

  auto body = [&](int s) {
    float2v Bv[8], Cv[8];
#pragma unroll
    for (int j = 0; j < 8; ++j) {
      Bv[j] = *(const float2v*)(xdb + (size_t)s * 48 + 2 * j);
      Cv[j] = *(const float2v*)(xdb + (size_t)s * 48 + 16 + 2 * j);
    }
    float dlt = bf2f(dp[(size_t)s * DIM]);
    float xcv = bf2f(xcp[(size_t)s * DIM]);
    float2v dlt2 = (float2v){dlt, dlt};
    float2v xcv2 = (float2v){xcv, xcv};
    float2v y2[4];
#pragma unroll
    for (int i = 0; i < 4; ++i) y2[i] = (float2v){0.f, 0.f};
#pragma unroll
    for (int i = 0; i < 8; ++i) {
      float2v arg = pk_mul_vv(dlt2, A2L[i]);
      float e0 = exp2_raw(arg.x), e1 = exp2_raw(arg.y);
      float2v e2 = (float2v){e0, e1};
      h2[i] = pk_fma_vvv(h2[i], e2, pk_mul_sv(Bv[i], xcv2));
      y2[i & 3] = pk_fma_vsv(h2[i], Cv[i], y2[i & 3]);
    }
    float2v s01 = pk_add_vv(y2[0], y2[1]);
    float2v s23 = pk_add_vv(y2[2], y2[3]);
    float2v st = pk_add_vv(s01, s23);
    yp[(size_t)s * DIM] = f2bf(st.x + st.y);
  };

  if (nst == CS) {
#pragma unroll
    for (int s = 0; s < CS; ++s) body(s);
  } else {
    for (int s = 0; s < nst; ++s) body(s);
  }
}

// ---------------- launch ----------------
extern "C" void kernel_launch(void* const* d_in, const int* in_sizes, int n_in,
                              void* d_out, int out_size, void* d_ws, size_t ws_size,
                              hipStream_t stream) {
  const float* x      = (const float*)d_in[0];
  const float* W_in   = (const float*)d_in[1];
  const float* b_in   = (const float*)d_in[2];
  const float* conv_w = (const float*)d_in[3];
  const float* conv_b = (const float*)d_in[4];
  const float* W_x    = (const float*)d_in[5];
  const float* W_dt   = (const float*)d_in[6];
  const float* b_dt   = (const float*)d_in[7];
  const float* W_out  = (const float*)d_in[8];
  const float* b_out  = (const float*)d_in[9];

  char* w = (char*)d_ws;
  // region 0 (67.63 MB): xp (LPAD layout) -> delta [M2P][DIM] -> y (in-place over delta)
  unsigned short* xp    = (unsigned short*)w;
  unsigned short* delta = (unsigned short*)w;
  unsigned short* ybuf  = (unsigned short*)w;
  size_t off = (size_t)M2P * DIM * 2;                                  // 67,633,152
  unsigned short* xcb  = (unsigned short*)(w + off); off += (size_t)M2P * DIM * 2;
  size_t xA_off = off;                                                 // 135,266,304
  unsigned short* xA   = (unsigned short*)(w + off); off += (size_t)16384 * 1024 * 2;
  unsigned short* wInB = (unsigned short*)(w + off); off += (size_t)2048 * 1024 * 2;
  unsigned short* wOutB= (unsigned short*)(w + off); off += (size_t)1024 * 2048 * 2;
  unsigned short* wXB  = (unsigned short*)(w + off); off += (size_t)128 * 2048 * 2;
  float* xdbl          = (float*)(w + off);          off += (size_t)M2 * 48 * 4;
  // xA region (37.5 MB, dead after gemm<0>) reused twice:
  //  1) split-K partials (8 * M2P * 48 * 4 = 25.4 MB) between gemm<1> and reduce
  //  2) sdbuf (2.13 MB) + qbuf (34.08 MB) bf16 from scan_pass1 onward
  float* part           = (float*)(w + xA_off);
  unsigned short* sdbuf = (unsigned short*)(w + xA_off);
  unsigned short* qbuf  = (unsigned short*)(w + xA_off + (size_t)B8 * NCH * 2048 * 2);
  (void)ws_size; (void)in_sizes; (void)n_in; (void)out_size;

  init_kernel<<<10336, 256, 0, stream>>>(x, W_in, W_out, W_x, xA, wInB, wOutB, wXB, xp);

  // gemm<0>: 128 bm tiles exact (8 blocks/CU)
  gemm_bt<0, 128, 16, 16, 0, 0><<<2048, 256, 0, stream>>>(xA, wInB, b_in, xp, 1024);
  conv_kernel<<<dim3(129, B8), 256, 0, stream>>>(xp, conv_w, conv_b, xcb);
  // gemm<1>: split-K=8 (ks = gid&7 == XCD), partials -> part, then deterministic reduce
  gemm_bt<1, 129, 1, 0, 0, 1><<<1032, 256, 0, stream>>>(xcb, wXB, nullptr, part, 2048);
  reduce_xdbl<<<770, 256, 0, stream>>>(part, xdbl);
  delta_kernel<<<dim3(2051, 8), 256, 0, stream>>>(xdbl, W_dt, b_dt, delta);

  scan_pass1<<<4160, 256, 0, stream>>>(xcb, delta, xdbl, sdbuf, qbuf);
  scan_boundary<<<dim3(128, B8), 256, 0, stream>>>(sdbuf, qbuf);
  scan_pass2<<<4160, 256, 0, stream>>>(xcb, delta, xdbl, qbuf, ybuf);

  // gemm<2>: banded 1024 + 8 integrated tail blocks (bm=128, bn=0..7)
  gemm_bt<2, 129, 8, 16, 1, 0><<<1032, 256, 0, stream>>>(ybuf, wOutB, b_out, (float*)d_out, 2048);
}

// Round 16
// 506.771 us; speedup vs baseline: 1.1181x; 1.0235x over previous
//
#include <hip/hip_runtime.h>
#include <cstdint>
#include <cstddef>

#define B8 8
#define LSEQ 2048
#define LC 2051
#define DMODEL 1024
#define DIM 2048
#define LPAD 2054           // 3 + 2048 + 3 zero-padded rows per batch
#define M2 16408            // B8*LC valid rows
#define M2P 16512           // padded to multiple of 128
#define CS 32               // scan chunk size
#define NCH 65              // ceil(2051/32)

typedef __attribute__((ext_vector_type(8))) short short8;
typedef __attribute__((ext_vector_type(4))) float floatx4;
typedef __attribute__((ext_vector_type(2))) float float2v;

// A_n = -exp(-n/3), n=0..15
__device__ __constant__ float AeT[16] = {
  -1.0f,          -0.71653131f, -0.51341712f, -0.36787944f,
  -0.26359714f,   -0.18887560f, -0.13533528f, -0.09697208f,
  -0.06948345f,   -0.04978707f, -0.03567399f, -0.02556154f,
  -0.01831564f,   -0.01312373f, -0.00940356f, -0.00673795f};

#define LOG2E 1.44269504088896f

__device__ __forceinline__ float bf2f(unsigned short h) {
  union { unsigned int u; float f; } v; v.u = ((unsigned int)h) << 16; return v.f;
}
__device__ __forceinline__ unsigned short f2bf(float f) {
  union { float f; unsigned int u; } v; v.f = f;
  unsigned int r = (v.u + 0x7FFFu + ((v.u >> 16) & 1u)) >> 16;
  return (unsigned short)r;
}

// ---- packed fp32 helpers (VOP3P). One scalar operand allowed per instr. ----
__device__ __forceinline__ float2v pk_mul_vv(float2v a, float2v b) {
  float2v d; asm("v_pk_mul_f32 %0, %1, %2" : "=v"(d) : "v"(a), "v"(b)); return d;
}
__device__ __forceinline__ float2v pk_mul_sv(float2v bs, float2v a) {   // bs wave-uniform (SGPR)
  float2v d; asm("v_pk_mul_f32 %0, %1, %2" : "=v"(d) : "s"(bs), "v"(a)); return d;
}
__device__ __forceinline__ float2v pk_fma_vvv(float2v a, float2v b, float2v c) {
  float2v d; asm("v_pk_fma_f32 %0, %1, %2, %3" : "=v"(d) : "v"(a), "v"(b), "v"(c)); return d;
}
__device__ __forceinline__ float2v pk_fma_vsv(float2v a, float2v bs, float2v c) { // bs uniform
  float2v d; asm("v_pk_fma_f32 %0, %1, %2, %3" : "=v"(d) : "v"(a), "s"(bs), "v"(c)); return d;
}
__device__ __forceinline__ float2v pk_add_vv(float2v a, float2v b) {
  float2v d; asm("v_pk_add_f32 %0, %1, %2" : "=v"(d) : "v"(a), "v"(b)); return d;
}
__device__ __forceinline__ float exp2_raw(float x) {   // 2^x
  float d; asm("v_exp_f32 %0, %1" : "=v"(d) : "v"(x)); return d;
}

// ---------------- fused init: x->bf16, W_in/W_out/W_x->bf16, zero pads ----------------
__global__ __launch_bounds__(256) void init_kernel(const float* __restrict__ x,
                                                   const float* __restrict__ W_in,
                                                   const float* __restrict__ W_out,
                                                   const float* __restrict__ W_x,
                                                   unsigned short* __restrict__ xA,
                                                   unsigned short* __restrict__ wInB,
                                                   unsigned short* __restrict__ wOutB,
                                                   unsigned short* __restrict__ wXB,
                                                   unsigned short* __restrict__ xp) {
  const int gid = blockIdx.x;
  const float* in; unsigned short* out; int i;
  if (gid < 8192)        { in = x;     out = xA;    i = gid * 256 + threadIdx.x; }
  else if (gid < 9216)   { in = W_in;  out = wInB;  i = (gid - 8192) * 256 + threadIdx.x; }
  else if (gid < 10240)  { in = W_out; out = wOutB; i = (gid - 9216) * 256 + threadIdx.x; }
  else if (gid < 10288)  { in = W_x;   out = wXB;   i = (gid - 10240) * 256 + threadIdx.x; }
  else {
    int ii = (gid - 10288) * 256 + threadIdx.x;   // 0..12287
    int b = ii / 1536;
    int r6 = (ii % 1536) / 256;
    int dd = (ii % 256) * 8;
    int row = (r6 < 3) ? r6 : (2048 + r6);
    *(uint4*)(xp + ((size_t)b * LPAD + row) * DIM + dd) = make_uint4(0, 0, 0, 0);
    return;
  }
  const float4* p = (const float4*)in + (size_t)i * 2;
  float4 a = p[0], b = p[1];
  uint4 o;
  o.x = (unsigned)f2bf(a.x) | ((unsigned)f2bf(a.y) << 16);
  o.y = (unsigned)f2bf(a.z) | ((unsigned)f2bf(a.w) << 16);
  o.z = (unsigned)f2bf(b.x) | ((unsigned)f2bf(b.y) << 16);
  o.w = (unsigned)f2bf(b.z) | ((unsigned)f2bf(b.w) << 16);
  *((uint4*)out + i) = o;
}

// ---------------- depthwise conv1d, 16 t per block (sliding window) ----------------
__global__ __launch_bounds__(256) void conv_kernel(const unsigned short* __restrict__ xp,
                                                   const float* __restrict__ conv_w,
                                                   const float* __restrict__ conv_b,
                                                   unsigned short* __restrict__ xc) {
  const int tc0 = blockIdx.x * 16;
  const int b = blockIdx.y;
  const int d0 = threadIdx.x * 8;

  float4 cw[8];
#pragma unroll
  for (int j = 0; j < 8; ++j) cw[j] = *(const float4*)(conv_w + (size_t)(d0 + j) * 4);
  float cb[8];
  {
    const float4* cb4 = (const float4*)(conv_b + d0);
    float4 c0 = cb4[0], c1 = cb4[1];
    cb[0] = c0.x; cb[1] = c0.y; cb[2] = c0.z; cb[3] = c0.w;
    cb[4] = c1.x; cb[5] = c1.y; cb[6] = c1.z; cb[7] = c1.w;
  }

  const unsigned short* base = xp + ((size_t)b * LPAD + tc0) * DIM + d0;
  unsigned short* outp = xc + ((size_t)b * LC + tc0) * DIM + d0;

  auto loadrow = [&](float (&w)[8], int r) {
    uint4 v = *(const uint4*)(base + (size_t)r * DIM);
    w[0] = bf2f(v.x & 0xffff); w[1] = bf2f(v.x >> 16);
    w[2] = bf2f(v.y & 0xffff); w[3] = bf2f(v.y >> 16);
    w[4] = bf2f(v.z & 0xffff); w[5] = bf2f(v.z >> 16);
    w[6] = bf2f(v.w & 0xffff); w[7] = bf2f(v.w >> 16);
  };

  float wa[8], wb[8], wc[8];
  loadrow(wa, 0); loadrow(wb, 1); loadrow(wc, 2);
#pragma unroll
  for (int i = 0; i < 16; ++i) {
    float wd[8];
    loadrow(wd, i + 3);
    if (tc0 + i < LC) {
      float acc[8];
#pragma unroll
      for (int j = 0; j < 8; ++j) {
        acc[j] = cb[j];
        acc[j] = fmaf(wa[j], cw[j].x, acc[j]);
        acc[j] = fmaf(wb[j], cw[j].y, acc[j]);
        acc[j] = fmaf(wc[j], cw[j].z, acc[j]);
        acc[j] = fmaf(wd[j], cw[j].w, acc[j]);
      }
      uint4 o;
      o.x = (unsigned)f2bf(acc[0]) | ((unsigned)f2bf(acc[1]) << 16);
      o.y = (unsigned)f2bf(acc[2]) | ((unsigned)f2bf(acc[3]) << 16);
      o.z = (unsigned)f2bf(acc[4]) | ((unsigned)f2bf(acc[5]) << 16);
      o.w = (unsigned)f2bf(acc[6]) | ((unsigned)f2bf(acc[7]) << 16);
      *(uint4*)(outp + (size_t)i * DIM) = o;
    }
#pragma unroll
    for (int j = 0; j < 8; ++j) { wa[j] = wb[j]; wb[j] = wc[j]; wc[j] = wd[j]; }
  }
}

#define GAS(p) ((const __attribute__((address_space(1))) void*)(p))
#define LAS(p) ((__attribute__((address_space(3))) void*)(p))

// ---------------- bf16 MFMA GEMM, known-good: BK=64, 2-barrier, 0 conflicts ----------
// 128x128 tile, 4 waves. LDS [128][64] bf16, XOR-swizzled 16B blocks: phys = log ^ (row&7),
// inverse on global staging source, forward on reads (rule #21). 108-112 us, MfmaUtil 26%.
// Mapping: XCD-banded main; TAIL=1 appends extra bm row-tiles in SAME launch.
// SPLITK=1 (MODE 1): gid = bm*8+ks; each block does K/8; partials -> part[ks][r][48].
template <int MODE, int NBM, int NBN, int LX, int TAIL, int SPLITK>
__global__ __launch_bounds__(256) void gemm_bt(const unsigned short* __restrict__ A,
                                               const unsigned short* __restrict__ Bw,
                                               const float* __restrict__ bias,
                                               void* __restrict__ Cout, int K) {
  const int gid = blockIdx.x;
  const int mainBlocks = 8 * LX * NBN;
  int bm, bn, ks = 0;
  if constexpr (SPLITK) {
    ks = gid & 7;
    bm = gid >> 3;
    bn = 0;
  } else if (TAIL && gid >= mainBlocks) {
    const int e = gid - mainBlocks;
    bm = 8 * LX + e / NBN;
    bn = e % NBN;
  } else {
    const int xcd = gid & 7;
    const int j = gid >> 3;
    bm = xcd * LX + (j % LX);
    bn = j / LX;
  }
  if (bm >= NBM) return;

  __shared__ __align__(16) unsigned short As[128 * 64];   // 16KB
  __shared__ __align__(16) unsigned short Bs[128 * 64];   // 16KB
  const int tid = threadIdx.x;
  const int lane = tid & 63, wave = tid >> 6;
  const int wr = wave >> 1, wc = wave & 1;

  floatx4 acc[4][4];
#pragma unroll
  for (int i = 0; i < 4; ++i)
#pragma unroll
    for (int j2 = 0; j2 < 4; ++j2) acc[i][j2] = (floatx4){0.f, 0.f, 0.f, 0.f};

  // staging: load L covers line = L*256+tid; row = L*32 + (tid>>3), phys_blk = tid&7,
  // logical blk = phys ^ (row&7) = (tid&7)^((tid>>3)&7)  (inverse swizzle on global src).
  const int srow = tid >> 3;
  const int scol = ((tid & 7) ^ ((tid >> 3) & 7)) * 8;
  const unsigned short* Ab[4];
  const unsigned short* Bb[4];
#pragma unroll
  for (int L = 0; L < 4; ++L) {
    Ab[L] = A  + (size_t)(bm * 128 + L * 32 + srow) * K + scol;
    Bb[L] = Bw + (size_t)(bn * 128 + L * 32 + srow) * K + scol;
  }

  const int fr = lane & 15;
  const int hi = lane >> 4;
  const int fx = fr & 7;

  const int kbase = SPLITK ? ks * (K >> 3) : 0;
  const int kend = kbase + (SPLITK ? (K >> 3) : K);

  for (int k0 = kbase; k0 < kend; k0 += 64) {
    __syncthreads();  // previous compute done before overwrite
#pragma unroll
    for (int L = 0; L < 4; ++L) {
      __builtin_amdgcn_global_load_lds(GAS(Ab[L] + k0), LAS(As + L * 2048 + tid * 8), 16, 0, 0);
      __builtin_amdgcn_global_load_lds(GAS(Bb[L] + k0), LAS(Bs + L * 2048 + tid * 8), 16, 0, 0);
    }
    __syncthreads();  // drains vmcnt -> LDS ready

#pragma unroll
    for (int kk = 0; kk < 2; ++kk) {
      const int pb = ((kk * 4 + hi) ^ fx) * 8;
      short8 af[4], bf[4];
#pragma unroll
      for (int mt = 0; mt < 4; ++mt) af[mt] = *(const short8*)&As[(wr * 64 + mt * 16 + fr) * 64 + pb];
#pragma unroll
      for (int nt = 0; nt < 4; ++nt) bf[nt] = *(const short8*)&Bs[(wc * 64 + nt * 16 + fr) * 64 + pb];
#pragma unroll
      for (int mt = 0; mt < 4; ++mt)
#pragma unroll
        for (int nt = 0; nt < 4; ++nt)
          acc[mt][nt] = __builtin_amdgcn_mfma_f32_16x16x32_bf16(af[mt], bf[nt], acc[mt][nt], 0, 0, 0);
    }
  }

  const int er = (lane >> 4) * 4, ec = lane & 15;
#pragma unroll
  for (int mt = 0; mt < 4; ++mt) {
#pragma unroll
    for (int nt = 0; nt < 4; ++nt) {
#pragma unroll
      for (int i = 0; i < 4; ++i) {
        int r = bm * 128 + wr * 64 + mt * 16 + er + i;
        int c = bn * 128 + wc * 64 + nt * 16 + ec;
        float v = acc[mt][nt][i];
        if constexpr (MODE == 0) {
          int bb = r >> 11, t = r & 2047;
          ((unsigned short*)Cout)[((size_t)bb * LPAD + 3 + t) * DIM + c] = f2bf(v + bias[c]);
        } else if constexpr (MODE == 1) {
          if (c < 48) ((float*)Cout)[((size_t)ks * M2P + r) * 48 + c] = v;
        } else {
          if (r < M2) ((float*)Cout)[(size_t)r * DMODEL + c] = v + bias[c];
        }
      }
    }
  }
}

// ---------------- reduce split-K partials -> xdbl (deterministic, no atomics) ----------
__global__ __launch_bounds__(256) void reduce_xdbl(const float* __restrict__ part,
                                                   float* __restrict__ xdbl) {
  int i = blockIdx.x * 256 + threadIdx.x;     // float4 index over [M2][48]
  if (i >= 196896) return;                    // 16408*48/4
  float4 s = make_float4(0.f, 0.f, 0.f, 0.f);
#pragma unroll
  for (int ks = 0; ks < 8; ++ks) {
    float4 v = *(const float4*)(part + (size_t)ks * M2P * 48 + (size_t)i * 4);
    s.x += v.x; s.y += v.y; s.z += v.z; s.w += v.w;
  }
  *(float4*)(xdbl + (size_t)i * 4) = s;
}

// ---------------- delta precompute: softplus(d_raw @ W_dt.T + b_dt) -> bf16 ----------------
__global__ __launch_bounds__(256) void delta_kernel(const float* __restrict__ xdbl,
                                                    const float* __restrict__ W_dt,
                                                    const float* __restrict__ b_dt,
                                                    unsigned short* __restrict__ delta) {
  const int d = blockIdx.y * 256 + threadIdx.x;
  const int r0 = blockIdx.x * 8;
  float wv[16];
  const float4* wp = (const float4*)(W_dt + (size_t)d * 16);
#pragma unroll
  for (int q = 0; q < 4; ++q) {
    float4 t = wp[q];
    wv[q * 4 + 0] = t.x; wv[q * 4 + 1] = t.y; wv[q * 4 + 2] = t.z; wv[q * 4 + 3] = t.w;
  }
  const float bd = b_dt[d];
#pragma unroll
  for (int j = 0; j < 8; ++j) {
    const float* dr = xdbl + (size_t)(r0 + j) * 48;   // uniform -> s_load
    float z0 = bd, z1 = 0.f, z2 = 0.f, z3 = 0.f;
#pragma unroll
    for (int n = 0; n < 16; n += 4) {
      z0 = fmaf(dr[n + 0], wv[n + 0], z0);
      z1 = fmaf(dr[n + 1], wv[n + 1], z1);
      z2 = fmaf(dr[n + 2], wv[n + 2], z2);
      z3 = fmaf(dr[n + 3], wv[n + 3], z3);
    }
    float z = (z0 + z1) + (z2 + z3);
    float dl = (z > 20.f) ? z : __logf(1.f + __expf(z));
    delta[(size_t)(r0 + j) * DIM + d] = f2bf(dl);
  }
}

// ---------------- chunked scan, pass 1: per-chunk (sumd, q) -> bf16 ----------------
// __launch_bounds__(256, 4): cap occupancy demand at 4 waves/EU (16/CU) -> VGPR budget
// doubles (56 -> up to 128), letting the scheduler pipeline the per-step s_load/exp
// stream several steps deep (the r15 counters showed 31% VALU stall at VGPR=56).
__global__ __launch_bounds__(256, 4) void scan_pass1(const unsigned short* __restrict__ xc,
                                                     const unsigned short* __restrict__ dl,
                                                     const float* __restrict__ xd,
                                                     unsigned short* __restrict__ sdbuf,
                                                     unsigned short* __restrict__ qbuf) {
  const int wid = __builtin_amdgcn_readfirstlane((int)(threadIdx.x >> 6));
  const int lane = threadIdx.x & 63;
  const int W = blockIdx.x * 4 + wid;
  const int dg = W & 31;
  const int rest = W >> 5;
  const int c = rest % NCH;
  const int b = rest / NCH;
  const int d = dg * 64 + lane;
  const int t0 = c * CS;
  const int nst = (t0 + CS <= LC) ? CS : (LC - t0);

  float2v A2L[8];
#pragma unroll
  for (int i = 0; i < 8; ++i)
    A2L[i] = (float2v){AeT[2 * i] * LOG2E, AeT[2 * i + 1] * LOG2E};

  float2v h2[8];
#pragma unroll
  for (int i = 0; i < 8; ++i) h2[i] = (float2v){0.f, 0.f};
  float sumd = 0.f;

  const size_t row0 = (size_t)b * LC + t0;
  const float* xdb = xd + row0 * 48 + 16;            // B cols (uniform -> s_load)
  const unsigned short* xcp = xc + row0 * DIM + d;
  const unsigned short* dp  = dl + row0 * DIM + d;

  auto body = [&](int s) {
    float2v Bv[8];
#pragma unroll
    for (int j = 0; j < 8; ++j) Bv[j] = *(const float2v*)(xdb + (size_t)s * 48 + 2 * j);
    float dlt = bf2f(dp[(size_t)s * DIM]);
    float xcv = bf2f(xcp[(size_t)s * DIM]);
    sumd += dlt;
    float2v dlt2 = (float2v){dlt, dlt};
    float2v xcv2 = (float2v){xcv, xcv};
#pragma unroll
    for (int i = 0; i < 8; ++i) {
      float2v arg = pk_mul_vv(dlt2, A2L[i]);
      float e0 = exp2_raw(arg.x), e1 = exp2_raw(arg.y);
      float2v e2 = (float2v){e0, e1};
      h2[i] = pk_fma_vvv(h2[i], e2, pk_mul_sv(Bv[i], xcv2));
    }
  };

  if (nst == CS) {
#pragma unroll
    for (int s = 0; s < CS; ++s) body(s);
  } else {
    for (int s = 0; s < nst; ++s) body(s);
  }

  sdbuf[((size_t)(b * NCH + c) << 11) + d] = f2bf(sumd);
  const size_t base = ((size_t)(b * NCH + c) * 16) * 2048 + d;
#pragma unroll
  for (int i = 0; i < 8; ++i) {
    qbuf[base + ((size_t)(2 * i) << 11)]     = f2bf(h2[i].x);
    qbuf[base + ((size_t)(2 * i + 1) << 11)] = f2bf(h2[i].y);
  }
}

// ---------------- boundary scan: 1 lane per (b,d,n); h across chunks, h_init over q ----
__global__ __launch_bounds__(256) void scan_boundary(const unsigned short* __restrict__ sdbuf,
                                                     unsigned short* __restrict__ qbuf) {
  const int tid = threadIdx.x;
  const int n = tid >> 4;
  const int d = blockIdx.x * 16 + (tid & 15);
  const int b = blockIdx.y;
  const float aL = AeT[n] * LOG2E;
  float h = 0.f;
  for (int c = 0; c < NCH; ++c) {
    const size_t sbase = ((size_t)(b * NCH + c) << 11);
    const float sd = bf2f(sdbuf[sbase + d]);
    const size_t base = (sbase << 4) + ((size_t)n << 11) + d;
    const float qv = bf2f(qbuf[base]);
    const float Pv = exp2_raw(sd * aL);
    qbuf[base] = f2bf(h);
    h = fmaf(Pv, h, qv);
  }
}

// ---------------- chunked scan, pass 2: recompute with h_init, emit y ----------------
// NOTE: y aliases dl (in-place, same [r][d] layout); only the owning thread touches
// each element and reads precede the store for that row.
__global__ __launch_bounds__(256, 4) void scan_pass2(const unsigned short* __restrict__ xc,
                                                     const unsigned short* __restrict__ dl,
                                                     const float* __restrict__ xd,
                                                     const unsigned short* __restrict__ hinit,
                                                     unsigned short* __restrict__ y) {
  const int wid = __builtin_amdgcn_readfirstlane((int)(threadIdx.x >> 6));
  const int lane = threadIdx.x & 63;
  const int W = blockIdx.x * 4 + wid;
  const int dg = W & 31;
  const int rest = W >> 5;
  const int c = rest % NCH;
  const int b = rest / NCH;
  const int d = dg * 64 + lane;
  const int t0 = c * CS;
  const int nst = (t0 + CS <= LC) ? CS : (LC - t0);

  float2v A2L[8];
#pragma unroll
  for (int i = 0; i < 8; ++i)
    A2L[i] = (float2v){AeT[2 * i] * LOG2E, AeT[2 * i + 1] * LOG2E};

  const size_t base = ((size_t)(b * NCH + c) * 16) * 2048 + d;
  float2v h2[8];
#pragma unroll
  for (int i = 0; i < 8; ++i)
    h2[i] = (float2v){bf2f(hinit[base + ((size_t)(2 * i) << 11)]),
                      bf2f(hinit[base + ((size_t)(2 * i + 1) << 11)])};

  const size_t row0 = (size_t)b * LC + t0;
  const float* xdb = xd + row0 * 48 + 16;            // B at [j], C at [16+j]
  const unsigned short* xcp = xc + row0 * DIM + d;
  const unsigned short* dp  = dl + row0 * DIM + d;
  unsigned short* yp = y + row0 * DIM + d;

  auto body = [&](int s) {
    float2v Bv[8], Cv[8];
#pragma unroll
    for (int j = 0; j < 8; ++j) {
      Bv[j] = *(const float2v*)(xdb + (size_t)s * 48 + 2 * j);
      Cv[j] = *(const float2v*)(xdb + (size_t)s * 48 + 16 + 2 * j);
    }
    float dlt = bf2f(dp[(size_t)s * DIM]);
    float xcv = bf2f(xcp[(size_t)s * DIM]);
    float2v dlt2 = (float2v){dlt, dlt};
    float2v xcv2 = (float2v){xcv, xcv};
    float2v y2[4];
#pragma unroll
    for (int i = 0; i < 4; ++i) y2[i] = (float2v){0.f, 0.f};
#pragma unroll
    for (int i = 0; i < 8; ++i) {
      float2v arg = pk_mul_vv(dlt2, A2L[i]);
      float e0 = exp2_raw(arg.x), e1 = exp2_raw(arg.y);
      float2v e2 = (float2v){e0, e1};
      h2[i] = pk_fma_vvv(h2[i], e2, pk_mul_sv(Bv[i], xcv2));
      y2[i & 3] = pk_fma_vsv(h2[i], Cv[i], y2[i & 3]);
    }
    float2v s01 = pk_add_vv(y2[0], y2[1]);
    float2v s23 = pk_add_vv(y2[2], y2[3]);
    float2v st = pk_add_vv(s01, s23);
    yp[(size_t)s * DIM] = f2bf(st.x + st.y);
  };

  if (nst == CS) {
#pragma unroll
    for (int s = 0; s < CS; ++s) body(s);
  } else {
    for (int s = 0; s < nst; ++s) body(s);
  }
}

// ---------------- launch ----------------
extern "C" void kernel_launch(void* const* d_in, const int* in_sizes, int n_in,
                              void* d_out, int out_size, void* d_ws, size_t ws_size,
                              hipStream_t stream) {
  const float* x      = (const float*)d_in[0];
  const float* W_in   = (const float*)d_in[1];
  const float* b_in   = (const float*)d_in[2];
  const float* conv_w = (const float*)d_in[3];
  const float* conv_b = (const float*)d_in[4];
  const float* W_x    = (const float*)d_in[5];
  const float* W_dt   = (const float*)d_in[6];
  const float* b_dt   = (const float*)d_in[7];
  const float* W_out  = (const float*)d_in[8];
  const float* b_out  = (const float*)d_in[9];

  char* w = (char*)d_ws;
  // region 0 (67.63 MB): xp (LPAD layout) -> delta [M2P][DIM] -> y (in-place over delta)
  unsigned short* xp    = (unsigned short*)w;
  unsigned short* delta = (unsigned short*)w;
  unsigned short* ybuf  = (unsigned short*)w;
  size_t off = (size_t)M2P * DIM * 2;                                  // 67,633,152
  unsigned short* xcb  = (unsigned short*)(w + off); off += (size_t)M2P * DIM * 2;
  size_t xA_off = off;                                                 // 135,266,304
  unsigned short* xA   = (unsigned short*)(w + off); off += (size_t)16384 * 1024 * 2;
  unsigned short* wInB = (unsigned short*)(w + off); off += (size_t)2048 * 1024 * 2;
  unsigned short* wOutB= (unsigned short*)(w + off); off += (size_t)1024 * 2048 * 2;
  unsigned short* wXB  = (unsigned short*)(w + off); off += (size_t)128 * 2048 * 2;
  float* xdbl          = (float*)(w + off);          off += (size_t)M2 * 48 * 4;
  // xA region (37.5 MB, dead after gemm<0>) reused twice:
  //  1) split-K partials (8 * M2P * 48 * 4 = 25.4 MB) between gemm<1> and reduce
  //  2) sdbuf (2.13 MB) + qbuf (34.08 MB) bf16 from scan_pass1 onward
  float* part           = (float*)(w + xA_off);
  unsigned short* sdbuf = (unsigned short*)(w + xA_off);
  unsigned short* qbuf  = (unsigned short*)(w + xA_off + (size_t)B8 * NCH * 2048 * 2);
  (void)ws_size; (void)in_sizes; (void)n_in; (void)out_size;

  init_kernel<<<10336, 256, 0, stream>>>(x, W_in, W_out, W_x, xA, wInB, wOutB, wXB, xp);

  // gemm<0>: 128 bm tiles exact (8 blocks/CU)
  gemm_bt<0, 128, 16, 16, 0, 0><<<2048, 256, 0, stream>>>(xA, wInB, b_in, xp, 1024);
  conv_kernel<<<dim3(129, B8), 256, 0, stream>>>(xp, conv_w, conv_b, xcb);
  // gemm<1>: split-K=8 (ks = gid&7 == XCD), partials -> part, then deterministic reduce
  gemm_bt<1, 129, 1, 0, 0, 1><<<1032, 256, 0, stream>>>(xcb, wXB, nullptr, part, 2048);
  reduce_xdbl<<<770, 256, 0, stream>>>(part, xdbl);
  delta_kernel<<<dim3(2051, 8), 256, 0, stream>>>(xdbl, W_dt, b_dt, delta);

  scan_pass1<<<4160, 256, 0, stream>>>(xcb, delta, xdbl, sdbuf, qbuf);
  scan_boundary<<<dim3(128, B8), 256, 0, stream>>>(sdbuf, qbuf);
  scan_pass2<<<4160, 256, 0, stream>>>(xcb, delta, xdbl, qbuf, ybuf);

  // gemm<2>: banded 1024 + 8 integrated tail blocks (bm=128, bn=0..7)
  gemm_bt<2, 129, 8, 16, 1, 0><<<1032, 256, 0, stream>>>(ybuf, wOutB, b_out, (float*)d_out, 2048);
}

// Round 17
// 496.624 us; speedup vs baseline: 1.1409x; 1.0204x over previous
//
#include <hip/hip_runtime.h>
#include <cstdint>
#include <cstddef>

#define B8 8
#define LSEQ 2048
#define LC 2051
#define DMODEL 1024
#define DIM 2048
#define LPAD 2054           // 3 + 2048 + 3 zero-padded rows per batch
#define M2 16408            // B8*LC valid rows
#define M2P 16512           // padded to multiple of 128
#define CS 32               // scan chunk size
#define NCH 65              // ceil(2051/32)

typedef __attribute__((ext_vector_type(8))) short short8;
typedef __attribute__((ext_vector_type(4))) float floatx4;
typedef __attribute__((ext_vector_type(2))) float float2v;

// A_n = -exp(-n/3), n=0..15
__device__ __constant__ float AeT[16] = {
  -1.0f,          -0.71653131f, -0.51341712f, -0.36787944f,
  -0.26359714f,   -0.18887560f, -0.13533528f, -0.09697208f,
  -0.06948345f,   -0.04978707f, -0.03567399f, -0.02556154f,
  -0.01831564f,   -0.01312373f, -0.00940356f, -0.00673795f};

#define LOG2E 1.44269504088896f

__device__ __forceinline__ float bf2f(unsigned short h) {
  union { unsigned int u; float f; } v; v.u = ((unsigned int)h) << 16; return v.f;
}
__device__ __forceinline__ unsigned short f2bf(float f) {
  union { float f; unsigned int u; } v; v.f = f;
  unsigned int r = (v.u + 0x7FFFu + ((v.u >> 16) & 1u)) >> 16;
  return (unsigned short)r;
}

// ---- packed fp32 helpers (VOP3P). One scalar operand allowed per instr. ----
__device__ __forceinline__ float2v pk_mul_vv(float2v a, float2v b) {
  float2v d; asm("v_pk_mul_f32 %0, %1, %2" : "=v"(d) : "v"(a), "v"(b)); return d;
}
__device__ __forceinline__ float2v pk_mul_sv(float2v bs, float2v a) {   // bs wave-uniform (SGPR)
  float2v d; asm("v_pk_mul_f32 %0, %1, %2" : "=v"(d) : "s"(bs), "v"(a)); return d;
}
__device__ __forceinline__ float2v pk_fma_vvv(float2v a, float2v b, float2v c) {
  float2v d; asm("v_pk_fma_f32 %0, %1, %2, %3" : "=v"(d) : "v"(a), "v"(b), "v"(c)); return d;
}
__device__ __forceinline__ float2v pk_fma_vsv(float2v a, float2v bs, float2v c) { // bs uniform
  float2v d; asm("v_pk_fma_f32 %0, %1, %2, %3" : "=v"(d) : "v"(a), "s"(bs), "v"(c)); return d;
}
__device__ __forceinline__ float2v pk_add_vv(float2v a, float2v b) {
  float2v d; asm("v_pk_add_f32 %0, %1, %2" : "=v"(d) : "v"(a), "v"(b)); return d;
}
__device__ __forceinline__ float exp2_raw(float x) {   // 2^x
  float d; asm("v_exp_f32 %0, %1" : "=v"(d) : "v"(x)); return d;
}

// ---------------- fused init: x->bf16, W_in/W_out/W_x->bf16, zero pads ----------------
__global__ __launch_bounds__(256) void init_kernel(const float* __restrict__ x,
                                                   const float* __restrict__ W_in,
                                                   const float* __restrict__ W_out,
                                                   const float* __restrict__ W_x,
                                                   unsigned short* __restrict__ xA,
                                                   unsigned short* __restrict__ wInB,
                                                   unsigned short* __restrict__ wOutB,
                                                   unsigned short* __restrict__ wXB,
                                                   unsigned short* __restrict__ xp) {
  const int gid = blockIdx.x;
  const float* in; unsigned short* out; int i;
  if (gid < 8192)        { in = x;     out = xA;    i = gid * 256 + threadIdx.x; }
  else if (gid < 9216)   { in = W_in;  out = wInB;  i = (gid - 8192) * 256 + threadIdx.x; }
  else if (gid < 10240)  { in = W_out; out = wOutB; i = (gid - 9216) * 256 + threadIdx.x; }
  else if (gid < 10288)  { in = W_x;   out = wXB;   i = (gid - 10240) * 256 + threadIdx.x; }
  else {
    int ii = (gid - 10288) * 256 + threadIdx.x;   // 0..12287
    int b = ii / 1536;
    int r6 = (ii % 1536) / 256;
    int dd = (ii % 256) * 8;
    int row = (r6 < 3) ? r6 : (2048 + r6);
    *(uint4*)(xp + ((size_t)b * LPAD + row) * DIM + dd) = make_uint4(0, 0, 0, 0);
    return;
  }
  const float4* p = (const float4*)in + (size_t)i * 2;
  float4 a = p[0], b = p[1];
  uint4 o;
  o.x = (unsigned)f2bf(a.x) | ((unsigned)f2bf(a.y) << 16);
  o.y = (unsigned)f2bf(a.z) | ((unsigned)f2bf(a.w) << 16);
  o.z = (unsigned)f2bf(b.x) | ((unsigned)f2bf(b.y) << 16);
  o.w = (unsigned)f2bf(b.z) | ((unsigned)f2bf(b.w) << 16);
  *((uint4*)out + i) = o;
}

// ---------------- depthwise conv1d, 16 t per block (sliding window) ----------------
__global__ __launch_bounds__(256) void conv_kernel(const unsigned short* __restrict__ xp,
                                                   const float* __restrict__ conv_w,
                                                   const float* __restrict__ conv_b,
                                                   unsigned short* __restrict__ xc) {
  const int tc0 = blockIdx.x * 16;
  const int b = blockIdx.y;
  const int d0 = threadIdx.x * 8;

  float4 cw[8];
#pragma unroll
  for (int j = 0; j < 8; ++j) cw[j] = *(const float4*)(conv_w + (size_t)(d0 + j) * 4);
  float cb[8];
  {
    const float4* cb4 = (const float4*)(conv_b + d0);
    float4 c0 = cb4[0], c1 = cb4[1];
    cb[0] = c0.x; cb[1] = c0.y; cb[2] = c0.z; cb[3] = c0.w;
    cb[4] = c1.x; cb[5] = c1.y; cb[6] = c1.z; cb[7] = c1.w;
  }

  const unsigned short* base = xp + ((size_t)b * LPAD + tc0) * DIM + d0;
  unsigned short* outp = xc + ((size_t)b * LC + tc0) * DIM + d0;

  auto loadrow = [&](float (&w)[8], int r) {
    uint4 v = *(const uint4*)(base + (size_t)r * DIM);
    w[0] = bf2f(v.x & 0xffff); w[1] = bf2f(v.x >> 16);
    w[2] = bf2f(v.y & 0xffff); w[3] = bf2f(v.y >> 16);
    w[4] = bf2f(v.z & 0xffff); w[5] = bf2f(v.z >> 16);
    w[6] = bf2f(v.w & 0xffff); w[7] = bf2f(v.w >> 16);
  };

  float wa[8], wb[8], wc[8];
  loadrow(wa, 0); loadrow(wb, 1); loadrow(wc, 2);
#pragma unroll
  for (int i = 0; i < 16; ++i) {
    float wd[8];
    loadrow(wd, i + 3);
    if (tc0 + i < LC) {
      float acc[8];
#pragma unroll
      for (int j = 0; j < 8; ++j) {
        acc[j] = cb[j];
        acc[j] = fmaf(wa[j], cw[j].x, acc[j]);
        acc[j] = fmaf(wb[j], cw[j].y, acc[j]);
        acc[j] = fmaf(wc[j], cw[j].z, acc[j]);
        acc[j] = fmaf(wd[j], cw[j].w, acc[j]);
      }
      uint4 o;
      o.x = (unsigned)f2bf(acc[0]) | ((unsigned)f2bf(acc[1]) << 16);
      o.y = (unsigned)f2bf(acc[2]) | ((unsigned)f2bf(acc[3]) << 16);
      o.z = (unsigned)f2bf(acc[4]) | ((unsigned)f2bf(acc[5]) << 16);
      o.w = (unsigned)f2bf(acc[6]) | ((unsigned)f2bf(acc[7]) << 16);
      *(uint4*)(outp + (size_t)i * DIM) = o;
    }
#pragma unroll
    for (int j = 0; j < 8; ++j) { wa[j] = wb[j]; wb[j] = wc[j]; wc[j] = wd[j]; }
  }
}

#define GAS(p) ((const __attribute__((address_space(1))) void*)(p))
#define LAS(p) ((__attribute__((address_space(3))) void*)(p))

// ---------------- 128x128 BK=64 GEMM: kept for split-K MODE 1 only ----------------
template <int NBM, int SPLITK>
__global__ __launch_bounds__(256) void gemm_bt(const unsigned short* __restrict__ A,
                                               const unsigned short* __restrict__ Bw,
                                               void* __restrict__ Cout, int K) {
  const int gid = blockIdx.x;
  int bm, ks;
  ks = gid & 7;
  bm = gid >> 3;
  const int bn = 0;
  if (bm >= NBM) return;

  __shared__ __align__(16) unsigned short As[128 * 64];   // 16KB
  __shared__ __align__(16) unsigned short Bs[128 * 64];   // 16KB
  const int tid = threadIdx.x;
  const int lane = tid & 63, wave = tid >> 6;
  const int wr = wave >> 1, wc = wave & 1;

  floatx4 acc[4][4];
#pragma unroll
  for (int i = 0; i < 4; ++i)
#pragma unroll
    for (int j2 = 0; j2 < 4; ++j2) acc[i][j2] = (floatx4){0.f, 0.f, 0.f, 0.f};

  const int srow = tid >> 3;
  const int scol = ((tid & 7) ^ ((tid >> 3) & 7)) * 8;
  const unsigned short* Ab[4];
  const unsigned short* Bb[4];
#pragma unroll
  for (int L = 0; L < 4; ++L) {
    Ab[L] = A  + (size_t)(bm * 128 + L * 32 + srow) * K + scol;
    Bb[L] = Bw + (size_t)(bn * 128 + L * 32 + srow) * K + scol;
  }

  const int fr = lane & 15;
  const int hi = lane >> 4;
  const int fx = fr & 7;

  const int kbase = ks * (K >> 3);
  const int kend = kbase + (K >> 3);

  for (int k0 = kbase; k0 < kend; k0 += 64) {
    __syncthreads();
#pragma unroll
    for (int L = 0; L < 4; ++L) {
      __builtin_amdgcn_global_load_lds(GAS(Ab[L] + k0), LAS(As + L * 2048 + tid * 8), 16, 0, 0);
      __builtin_amdgcn_global_load_lds(GAS(Bb[L] + k0), LAS(Bs + L * 2048 + tid * 8), 16, 0, 0);
    }
    __syncthreads();

#pragma unroll
    for (int kk = 0; kk < 2; ++kk) {
      const int pb = ((kk * 4 + hi) ^ fx) * 8;
      short8 af[4], bf[4];
#pragma unroll
      for (int mt = 0; mt < 4; ++mt) af[mt] = *(const short8*)&As[(wr * 64 + mt * 16 + fr) * 64 + pb];
#pragma unroll
      for (int nt = 0; nt < 4; ++nt) bf[nt] = *(const short8*)&Bs[(wc * 64 + nt * 16 + fr) * 64 + pb];
#pragma unroll
      for (int mt = 0; mt < 4; ++mt)
#pragma unroll
        for (int nt = 0; nt < 4; ++nt)
          acc[mt][nt] = __builtin_amdgcn_mfma_f32_16x16x32_bf16(af[mt], bf[nt], acc[mt][nt], 0, 0, 0);
    }
  }

  const int er = (lane >> 4) * 4, ec = lane & 15;
#pragma unroll
  for (int mt = 0; mt < 4; ++mt) {
#pragma unroll
    for (int nt = 0; nt < 4; ++nt) {
#pragma unroll
      for (int i = 0; i < 4; ++i) {
        int r = bm * 128 + wr * 64 + mt * 16 + er + i;
        int c = bn * 128 + wc * 64 + nt * 16 + ec;
        float v = acc[mt][nt][i];
        if (c < 48) ((float*)Cout)[((size_t)ks * M2P + r) * 48 + c] = v;
      }
    }
  }
}

// ---------------- 256x128 BK=64 GEMM (same proven 2-barrier template, bigger tile) -----
// 8 waves (4Mx2N), per-wave 64x64 (acc[4][4]). LDS: A [256][64] 32KB + B [128][64] 16KB
// = 48KB -> 3 blocks/CU. FLOP per staged byte +33% vs 128x128. Swizzle identical:
// phys = log ^ (row&7); staging thread t covers lines L*512+t, row&7 = (t>>3)&7 for all L
// (64 == 0 mod 8), so the inverse-swizzled source col is the same for all L; fragment rows
// are wq*64 + mt*16 + fr -> row&7 == fr&7. 0 bank conflicts preserved.
// MODE 0: C bf16 -> xp LPAD, +bias (M=16384: NBM=64 exact). MODE 2: C fp32 -> out, +bias,
// mask r<M2 (NBM=65, tail tile reads allocated garbage rows, writes masked).
template <int MODE, int NBM, int NBN, int LX, int TAIL>
__global__ __launch_bounds__(512, 2) void gemm_big(const unsigned short* __restrict__ A,
                                                   const unsigned short* __restrict__ Bw,
                                                   const float* __restrict__ bias,
                                                   void* __restrict__ Cout, int K) {
  const int gid = blockIdx.x;
  const int mainBlocks = 8 * LX * NBN;
  int bm, bn;
  if (TAIL && gid >= mainBlocks) {
    const int e = gid - mainBlocks;
    bm = 8 * LX + e / NBN;
    bn = e % NBN;
  } else {
    const int xcd = gid & 7;
    const int j = gid >> 3;
    bm = xcd * LX + (j % LX);
    bn = j / LX;
  }
  if (bm >= NBM) return;

  __shared__ __align__(16) unsigned short As[256 * 64];   // 32KB
  __shared__ __align__(16) unsigned short Bs[128 * 64];   // 16KB
  const int tid = threadIdx.x;
  const int lane = tid & 63, wave = tid >> 6;   // wave 0..7
  const int wr = wave >> 1;                     // M quarter (64 rows)
  const int wc = wave & 1;                      // N half (64 cols)

  floatx4 acc[4][4];
#pragma unroll
  for (int i = 0; i < 4; ++i)
#pragma unroll
    for (int j2 = 0; j2 < 4; ++j2) acc[i][j2] = (floatx4){0.f, 0.f, 0.f, 0.f};

  // staging: thread t covers A lines {L*512+t, L=0..3}, B lines {L*512+t, L=0..1};
  // line l: row = l>>3, phys = l&7 -> row = L*64 + (t>>3), logical = (t&7)^((t>>3)&7).
  const int srow = tid >> 3;                        // 0..63
  const int scol = ((tid & 7) ^ ((tid >> 3) & 7)) * 8;
  const unsigned short* Ab[4];
  const unsigned short* Bb[2];
#pragma unroll
  for (int L = 0; L < 4; ++L)
    Ab[L] = A  + (size_t)(bm * 256 + L * 64 + srow) * K + scol;
#pragma unroll
  for (int L = 0; L < 2; ++L)
    Bb[L] = Bw + (size_t)(bn * 128 + L * 64 + srow) * K + scol;

  const int fr = lane & 15;
  const int hi = lane >> 4;
  const int fx = fr & 7;

  for (int k0 = 0; k0 < K; k0 += 64) {
    __syncthreads();  // previous compute done before overwrite
#pragma unroll
    for (int L = 0; L < 4; ++L)
      __builtin_amdgcn_global_load_lds(GAS(Ab[L] + k0), LAS(As + L * 4096 + tid * 8), 16, 0, 0);
#pragma unroll
    for (int L = 0; L < 2; ++L)
      __builtin_amdgcn_global_load_lds(GAS(Bb[L] + k0), LAS(Bs + L * 4096 + tid * 8), 16, 0, 0);
    __syncthreads();  // drains vmcnt -> LDS ready

#pragma unroll
    for (int kk = 0; kk < 2; ++kk) {
      const int pb = ((kk * 4 + hi) ^ fx) * 8;
      short8 af[4], bf[4];
#pragma unroll
      for (int mt = 0; mt < 4; ++mt) af[mt] = *(const short8*)&As[(wr * 64 + mt * 16 + fr) * 64 + pb];
#pragma unroll
      for (int nt = 0; nt < 4; ++nt) bf[nt] = *(const short8*)&Bs[(wc * 64 + nt * 16 + fr) * 64 + pb];
#pragma unroll
      for (int mt = 0; mt < 4; ++mt)
#pragma unroll
        for (int nt = 0; nt < 4; ++nt)
          acc[mt][nt] = __builtin_amdgcn_mfma_f32_16x16x32_bf16(af[mt], bf[nt], acc[mt][nt], 0, 0, 0);
    }
  }

  const int er = (lane >> 4) * 4, ec = lane & 15;
#pragma unroll
  for (int mt = 0; mt < 4; ++mt) {
#pragma unroll
    for (int nt = 0; nt < 4; ++nt) {
#pragma unroll
      for (int i = 0; i < 4; ++i) {
        int r = bm * 256 + wr * 64 + mt * 16 + er + i;
        int c = bn * 128 + wc * 64 + nt * 16 + ec;
        float v = acc[mt][nt][i];
        if constexpr (MODE == 0) {
          int bb = r >> 11, t = r & 2047;
          ((unsigned short*)Cout)[((size_t)bb * LPAD + 3 + t) * DIM + c] = f2bf(v + bias[c]);
        } else {
          if (r < M2) ((float*)Cout)[(size_t)r * DMODEL + c] = v + bias[c];
        }
      }
    }
  }
}

// ---------------- reduce split-K partials -> xdbl (deterministic, no atomics) ----------
__global__ __launch_bounds__(256) void reduce_xdbl(const float* __restrict__ part,
                                                   float* __restrict__ xdbl) {
  int i = blockIdx.x * 256 + threadIdx.x;     // float4 index over [M2][48]
  if (i >= 196896) return;                    // 16408*48/4
  float4 s = make_float4(0.f, 0.f, 0.f, 0.f);
#pragma unroll
  for (int ks = 0; ks < 8; ++ks) {
    float4 v = *(const float4*)(part + (size_t)ks * M2P * 48 + (size_t)i * 4);
    s.x += v.x; s.y += v.y; s.z += v.z; s.w += v.w;
  }
  *(float4*)(xdbl + (size_t)i * 4) = s;
}

// ---------------- delta precompute: softplus(d_raw @ W_dt.T + b_dt) -> bf16 ----------------
__global__ __launch_bounds__(256) void delta_kernel(const float* __restrict__ xdbl,
                                                    const float* __restrict__ W_dt,
                                                    const float* __restrict__ b_dt,
                                                    unsigned short* __restrict__ delta) {
  const int d = blockIdx.y * 256 + threadIdx.x;
  const int r0 = blockIdx.x * 8;
  float wv[16];
  const float4* wp = (const float4*)(W_dt + (size_t)d * 16);
#pragma unroll
  for (int q = 0; q < 4; ++q) {
    float4 t = wp[q];
    wv[q * 4 + 0] = t.x; wv[q * 4 + 1] = t.y; wv[q * 4 + 2] = t.z; wv[q * 4 + 3] = t.w;
  }
  const float bd = b_dt[d];
#pragma unroll
  for (int j = 0; j < 8; ++j) {
    const float* dr = xdbl + (size_t)(r0 + j) * 48;   // uniform -> s_load
    float z0 = bd, z1 = 0.f, z2 = 0.f, z3 = 0.f;
#pragma unroll
    for (int n = 0; n < 16; n += 4) {
      z0 = fmaf(dr[n + 0], wv[n + 0], z0);
      z1 = fmaf(dr[n + 1], wv[n + 1], z1);
      z2 = fmaf(dr[n + 2], wv[n + 2], z2);
      z3 = fmaf(dr[n + 3], wv[n + 3], z3);
    }
    float z = (z0 + z1) + (z2 + z3);
    float dl = (z > 20.f) ? z : __logf(1.f + __expf(z));
    delta[(size_t)(r0 + j) * DIM + d] = f2bf(dl);
  }
}

// ---------------- chunked scan, pass 1: per-chunk (sumd, q) -> bf16 ----------------
__global__ __launch_bounds__(256, 4) void scan_pass1(const unsigned short* __restrict__ xc,
                                                     const unsigned short* __restrict__ dl,
                                                     const float* __restrict__ xd,
                                                     unsigned short* __restrict__ sdbuf,
                                                     unsigned short* __restrict__ qbuf) {
  const int wid = __builtin_amdgcn_readfirstlane((int)(threadIdx.x >> 6));
  const int lane = threadIdx.x & 63;
  const int W = blockIdx.x * 4 + wid;
  const int dg = W & 31;
  const int rest = W >> 5;
  const int c = rest % NCH;
  const int b = rest / NCH;
  const int d = dg * 64 + lane;
  const int t0 = c * CS;
  const int nst = (t0 + CS <= LC) ? CS : (LC - t0);

  float2v A2L[8];
#pragma unroll
  for (int i = 0; i < 8; ++i)
    A2L[i] = (float2v){AeT[2 * i] * LOG2E, AeT[2 * i + 1] * LOG2E};

  float2v h2[8];
#pragma unroll
  for (int i = 0; i < 8; ++i) h2[i] = (float2v){0.f, 0.f};
  float sumd = 0.f;

  const size_t row0 = (size_t)b * LC + t0;
  const float* xdb = xd + row0 * 48 + 16;            // B cols (uniform -> s_load)
  const unsigned short* xcp = xc + row0 * DIM + d;
  const unsigned short* dp  = dl + row0 * DIM + d;

  auto body = [&](int s) {
    float2v Bv[8];
#pragma unroll
    for (int j = 0; j < 8; ++j) Bv[j] = *(const float2v*)(xdb + (size_t)s * 48 + 2 * j);
    float dlt = bf2f(dp[(size_t)s * DIM]);
    float xcv = bf2f(xcp[(size_t)s * DIM]);
    sumd += dlt;
    float2v dlt2 = (float2v){dlt, dlt};
    float2v xcv2 = (float2v){xcv, xcv};
#pragma unroll
    for (int i = 0; i < 8; ++i) {
      float2v arg = pk_mul_vv(dlt2, A2L[i]);
      float e0 = exp2_raw(arg.x), e1 = exp2_raw(arg.y);
      float2v e2 = (float2v){e0, e1};
      h2[i] = pk_fma_vvv(h2[i], e2, pk_mul_sv(Bv[i], xcv2));
    }
  };

  if (nst == CS) {
#pragma unroll
    for (int s = 0; s < CS; ++s) body(s);
  } else {
    for (int s = 0; s < nst; ++s) body(s);
  }

  sdbuf[((size_t)(b * NCH + c) << 11) + d] = f2bf(sumd);
  const size_t base = ((size_t)(b * NCH + c) * 16) * 2048 + d;
#pragma unroll
  for (int i = 0; i < 8; ++i) {
    qbuf[base + ((size_t)(2 * i) << 11)]     = f2bf(h2[i].x);
    qbuf[base + ((size_t)(2 * i + 1) << 11)] = f2bf(h2[i].y);
  }
}

// ---------------- boundary scan: 1 lane per (b,d,n); h across chunks, h_init over q ----
__global__ __launch_bounds__(256) void scan_boundary(const unsigned short* __restrict__ sdbuf,
                                                     unsigned short* __restrict__ qbuf) {
  const int tid = threadIdx.x;
  const int n = tid >> 4;
  const int d = blockIdx.x * 16 + (tid & 15);
  const int b = blockIdx.y;
  const float aL = AeT[n] * LOG2E;
  float h = 0.f;
  for (int c = 0; c < NCH; ++c) {
    const size_t sbase = ((size_t)(b * NCH + c) << 11);
    const float sd = bf2f(sdbuf[sbase + d]);
    const size_t base = (sbase << 4) + ((size_t)n << 11) + d;
    const float qv = bf2f(qbuf[base]);
    const float Pv = exp2_raw(sd * aL);
    qbuf[base] = f2bf(h);
    h = fmaf(Pv, h, qv);
  }
}

// ---------------- chunked scan, pass 2: recompute with h_init, emit y ----------------
// NOTE: y aliases dl (in-place, same [r][d] layout); only the owning thread touches
// each element and reads precede the store for that row.
__global__ __launch_bounds__(256, 4) void scan_pass2(const unsigned short* __restrict__ xc,
                                                     const unsigned short* __restrict__ dl,
                                                     const float* __restrict__ xd,
                                                     const unsigned short* __restrict__ hinit,
                                                     unsigned short* __restrict__ y) {
  const int wid = __builtin_amdgcn_readfirstlane((int)(threadIdx.x >> 6));
  const int lane = threadIdx.x & 63;
  const int W = blockIdx.x * 4 + wid;
  const int dg = W & 31;
  const int rest = W >> 5;
  const int c = rest % NCH;
  const int b = rest / NCH;
  const int d = dg * 64 + lane;
  const int t0 = c * CS;
  const int nst = (t0 + CS <= LC) ? CS : (LC - t0);

  float2v A2L[8];
#pragma unroll
  for (int i = 0; i < 8; ++i)
    A2L[i] = (float2v){AeT[2 * i] * LOG2E, AeT[2 * i + 1] * LOG2E};

  const size_t base = ((size_t)(b * NCH + c) * 16) * 2048 + d;
  float2v h2[8];
#pragma unroll
  for (int i = 0; i < 8; ++i)
    h2[i] = (float2v){bf2f(hinit[base + ((size_t)(2 * i) << 11)]),
                      bf2f(hinit[base + ((size_t)(2 * i + 1) << 11)])};

  const size_t row0 = (size_t)b * LC + t0;
  const float* xdb = xd + row0 * 48 + 16;            // B at [j], C at [16+j]
  const unsigned short* xcp = xc + row0 * DIM + d;
  const unsigned short* dp  = dl + row0 * DIM + d;
  unsigned short* yp = y + row0 * DIM + d;

  auto body = [&](int s) {
    float2v Bv[8], Cv[8];
#pragma unroll
    for (int j = 0; j < 8; ++j) {
      Bv[j] = *(const float2v*)(xdb + (size_t)s * 48 + 2 * j);
      Cv[j] = *(const float2v*)(xdb + (size_t)s * 48 + 16 + 2 * j);
    }
    float dlt = bf2f(dp[(size_t)s * DIM]);
    float xcv = bf2f(xcp[(size_t)s * DIM]);
    float2v dlt2 = (float2v){dlt, dlt};
    float2v xcv2 = (float2v){xcv, xcv};
    float2v y2[4];
#pragma unroll
    for (int i = 0; i < 4; ++i) y2[i] = (float2v){0.f, 0.f};
#pragma unroll
    for (int i = 0; i < 8; ++i) {
      float2v arg = pk_mul_vv(dlt2, A2L[i]);
      float e0 = exp2_raw(arg.x), e1 = exp2_raw(arg.y);
      float2v e2 = (float2v){e0, e1};
      h2[i] = pk_fma_vvv(h2[i], e2, pk_mul_sv(Bv[i], xcv2));
      y2[i & 3] = pk_fma_vsv(h2[i], Cv[i], y2[i & 3]);
    }
    float2v s01 = pk_add_vv(y2[0], y2[1]);
    float2v s23 = pk_add_vv(y2[2], y2[3]);
    float2v st = pk_add_vv(s01, s23);
    yp[(size_t)s * DIM] = f2bf(st.x + st.y);
  };

  if (nst == CS) {
#pragma unroll
    for (int s = 0; s < CS; ++s) body(s);
  } else {
    for (int s = 0; s < nst; ++s) body(s);
  }
}

// ---------------- launch ----------------
extern "C" void kernel_launch(void* const* d_in, const int* in_sizes, int n_in,
                              void* d_out, int out_size, void* d_ws, size_t ws_size,
                              hipStream_t stream) {
  const float* x      = (const float*)d_in[0];
  const float* W_in   = (const float*)d_in[1];
  const float* b_in   = (const float*)d_in[2];
  const float* conv_w = (const float*)d_in[3];
  const float* conv_b = (const float*)d_in[4];
  const float* W_x    = (const float*)d_in[5];
  const float* W_dt   = (const float*)d_in[6];
  const float* b_dt   = (const float*)d_in[7];
  const float* W_out  = (const float*)d_in[8];
  const float* b_out  = (const float*)d_in[9];

  char* w = (char*)d_ws;
  // region 0 (67.63 MB): xp (LPAD layout) -> delta [M2P][DIM] -> y (in-place over delta)
  unsigned short* xp    = (unsigned short*)w;
  unsigned short* delta = (unsigned short*)w;
  unsigned short* ybuf  = (unsigned short*)w;
  size_t off = (size_t)M2P * DIM * 2;                                  // 67,633,152
  unsigned short* xcb  = (unsigned short*)(w + off); off += (size_t)M2P * DIM * 2;
  size_t xA_off = off;                                                 // 135,266,304
  unsigned short* xA   = (unsigned short*)(w + off); off += (size_t)16384 * 1024 * 2;
  unsigned short* wInB = (unsigned short*)(w + off); off += (size_t)2048 * 1024 * 2;
  unsigned short* wOutB= (unsigned short*)(w + off); off += (size_t)1024 * 2048 * 2;
  unsigned short* wXB  = (unsigned short*)(w + off); off += (size_t)128 * 2048 * 2;
  float* xdbl          = (float*)(w + off);          off += (size_t)M2 * 48 * 4;
  // xA region (37.5 MB, dead after gemm<0>) reused twice:
  //  1) split-K partials (8 * M2P * 48 * 4 = 25.4 MB) between gemm<1> and reduce
  //  2) sdbuf (2.13 MB) + qbuf (34.08 MB) bf16 from scan_pass1 onward
  float* part           = (float*)(w + xA_off);
  unsigned short* sdbuf = (unsigned short*)(w + xA_off);
  unsigned short* qbuf  = (unsigned short*)(w + xA_off + (size_t)B8 * NCH * 2048 * 2);
  (void)ws_size; (void)in_sizes; (void)n_in; (void)out_size;

  init_kernel<<<10336, 256, 0, stream>>>(x, W_in, W_out, W_x, xA, wInB, wOutB, wXB, xp);

  // gemm<0>: 256x128 tiles, NBM=64 exact (LX=8), NBN=16 -> grid 1024 banded
  gemm_big<0, 64, 16, 8, 0><<<1024, 512, 0, stream>>>(xA, wInB, b_in, xp, 1024);
  conv_kernel<<<dim3(129, B8), 256, 0, stream>>>(xp, conv_w, conv_b, xcb);
  // gemm<1>: split-K=8 on 128-tile kernel, then deterministic reduce
  gemm_bt<129, 1><<<1032, 256, 0, stream>>>(xcb, wXB, part, 2048);
  reduce_xdbl<<<770, 256, 0, stream>>>(part, xdbl);
  delta_kernel<<<dim3(2051, 8), 256, 0, stream>>>(xdbl, W_dt, b_dt, delta);

  scan_pass1<<<4160, 256, 0, stream>>>(xcb, delta, xdbl, sdbuf, qbuf);
  scan_boundary<<<dim3(128, B8), 256, 0, stream>>>(sdbuf, qbuf);
  scan_pass2<<<4160, 256, 0, stream>>>(xcb, delta, xdbl, qbuf, ybuf);

  // gemm<2>: 256x128 tiles, NBM=65 (64 banded via LX=8 + 1 tail tile x NBN=8)
  gemm_big<2, 65, 8, 8, 1><<<520, 512, 0, stream>>>(ybuf, wOutB, b_out, (float*)d_out, 2048);
}

// Round 18
// 493.377 us; speedup vs baseline: 1.1484x; 1.0066x over previous
//
#include <hip/hip_runtime.h>
#include <cstdint>
#include <cstddef>

#define B8 8
#define LSEQ 2048
#define LC 2051
#define DMODEL 1024
#define DIM 2048
#define LPAD 2054           // 3 + 2048 + 3 zero-padded rows per batch
#define M2 16408            // B8*LC valid rows
#define M2P 16512           // padded to multiple of 128
#define CS 32               // scan chunk size
#define NCH 65              // ceil(2051/32)

typedef __attribute__((ext_vector_type(8))) short short8;
typedef __attribute__((ext_vector_type(4))) float floatx4;
typedef __attribute__((ext_vector_type(2))) float float2v;

// A_n = -exp(-n/3), n=0..15
__device__ __constant__ float AeT[16] = {
  -1.0f,          -0.71653131f, -0.51341712f, -0.36787944f,
  -0.26359714f,   -0.18887560f, -0.13533528f, -0.09697208f,
  -0.06948345f,   -0.04978707f, -0.03567399f, -0.02556154f,
  -0.01831564f,   -0.01312373f, -0.00940356f, -0.00673795f};

#define LOG2E 1.44269504088896f

__device__ __forceinline__ float bf2f(unsigned short h) {
  union { unsigned int u; float f; } v; v.u = ((unsigned int)h) << 16; return v.f;
}
__device__ __forceinline__ unsigned short f2bf(float f) {
  union { float f; unsigned int u; } v; v.f = f;
  unsigned int r = (v.u + 0x7FFFu + ((v.u >> 16) & 1u)) >> 16;
  return (unsigned short)r;
}

// ---- packed fp32 helpers (VOP3P). One scalar operand allowed per instr. ----
__device__ __forceinline__ float2v pk_mul_vv(float2v a, float2v b) {
  float2v d; asm("v_pk_mul_f32 %0, %1, %2" : "=v"(d) : "v"(a), "v"(b)); return d;
}
__device__ __forceinline__ float2v pk_mul_sv(float2v bs, float2v a) {   // bs wave-uniform (SGPR)
  float2v d; asm("v_pk_mul_f32 %0, %1, %2" : "=v"(d) : "s"(bs), "v"(a)); return d;
}
__device__ __forceinline__ float2v pk_fma_vvv(float2v a, float2v b, float2v c) {
  float2v d; asm("v_pk_fma_f32 %0, %1, %2, %3" : "=v"(d) : "v"(a), "v"(b), "v"(c)); return d;
}
__device__ __forceinline__ float2v pk_fma_vsv(float2v a, float2v bs, float2v c) { // bs uniform
  float2v d; asm("v_pk_fma_f32 %0, %1, %2, %3" : "=v"(d) : "v"(a), "s"(bs), "v"(c)); return d;
}
__device__ __forceinline__ float2v pk_add_vv(float2v a, float2v b) {
  float2v d; asm("v_pk_add_f32 %0, %1, %2" : "=v"(d) : "v"(a), "v"(b)); return d;
}
__device__ __forceinline__ float exp2_raw(float x) {   // 2^x
  float d; asm("v_exp_f32 %0, %1" : "=v"(d) : "v"(x)); return d;
}

// ---------------- fused init: x->bf16, W_in/W_out/W_x->bf16, zero pads ----------------
__global__ __launch_bounds__(256) void init_kernel(const float* __restrict__ x,
                                                   const float* __restrict__ W_in,
                                                   const float* __restrict__ W_out,
                                                   const float* __restrict__ W_x,
                                                   unsigned short* __restrict__ xA,
                                                   unsigned short* __restrict__ wInB,
                                                   unsigned short* __restrict__ wOutB,
                                                   unsigned short* __restrict__ wXB,
                                                   unsigned short* __restrict__ xp) {
  const int gid = blockIdx.x;
  const float* in; unsigned short* out; int i;
  if (gid < 8192)        { in = x;     out = xA;    i = gid * 256 + threadIdx.x; }
  else if (gid < 9216)   { in = W_in;  out = wInB;  i = (gid - 8192) * 256 + threadIdx.x; }
  else if (gid < 10240)  { in = W_out; out = wOutB; i = (gid - 9216) * 256 + threadIdx.x; }
  else if (gid < 10288)  { in = W_x;   out = wXB;   i = (gid - 10240) * 256 + threadIdx.x; }
  else {
    int ii = (gid - 10288) * 256 + threadIdx.x;   // 0..12287
    int b = ii / 1536;
    int r6 = (ii % 1536) / 256;
    int dd = (ii % 256) * 8;
    int row = (r6 < 3) ? r6 : (2048 + r6);
    *(uint4*)(xp + ((size_t)b * LPAD + row) * DIM + dd) = make_uint4(0, 0, 0, 0);
    return;
  }
  const float4* p = (const float4*)in + (size_t)i * 2;
  float4 a = p[0], b = p[1];
  uint4 o;
  o.x = (unsigned)f2bf(a.x) | ((unsigned)f2bf(a.y) << 16);
  o.y = (unsigned)f2bf(a.z) | ((unsigned)f2bf(a.w) << 16);
  o.z = (unsigned)f2bf(b.x) | ((unsigned)f2bf(b.y) << 16);
  o.w = (unsigned)f2bf(b.z) | ((unsigned)f2bf(b.w) << 16);
  *((uint4*)out + i) = o;
}

// ---------------- depthwise conv1d, 16 t per block (sliding window) ----------------
__global__ __launch_bounds__(256) void conv_kernel(const unsigned short* __restrict__ xp,
                                                   const float* __restrict__ conv_w,
                                                   const float* __restrict__ conv_b,
                                                   unsigned short* __restrict__ xc) {
  const int tc0 = blockIdx.x * 16;
  const int b = blockIdx.y;
  const int d0 = threadIdx.x * 8;

  float4 cw[8];
#pragma unroll
  for (int j = 0; j < 8; ++j) cw[j] = *(const float4*)(conv_w + (size_t)(d0 + j) * 4);
  float cb[8];
  {
    const float4* cb4 = (const float4*)(conv_b + d0);
    float4 c0 = cb4[0], c1 = cb4[1];
    cb[0] = c0.x; cb[1] = c0.y; cb[2] = c0.z; cb[3] = c0.w;
    cb[4] = c1.x; cb[5] = c1.y; cb[6] = c1.z; cb[7] = c1.w;
  }

  const unsigned short* base = xp + ((size_t)b * LPAD + tc0) * DIM + d0;
  unsigned short* outp = xc + ((size_t)b * LC + tc0) * DIM + d0;

  auto loadrow = [&](float (&w)[8], int r) {
    uint4 v = *(const uint4*)(base + (size_t)r * DIM);
    w[0] = bf2f(v.x & 0xffff); w[1] = bf2f(v.x >> 16);
    w[2] = bf2f(v.y & 0xffff); w[3] = bf2f(v.y >> 16);
    w[4] = bf2f(v.z & 0xffff); w[5] = bf2f(v.z >> 16);
    w[6] = bf2f(v.w & 0xffff); w[7] = bf2f(v.w >> 16);
  };

  float wa[8], wb[8], wc[8];
  loadrow(wa, 0); loadrow(wb, 1); loadrow(wc, 2);
#pragma unroll
  for (int i = 0; i < 16; ++i) {
    float wd[8];
    loadrow(wd, i + 3);
    if (tc0 + i < LC) {
      float acc[8];
#pragma unroll
      for (int j = 0; j < 8; ++j) {
        acc[j] = cb[j];
        acc[j] = fmaf(wa[j], cw[j].x, acc[j]);
        acc[j] = fmaf(wb[j], cw[j].y, acc[j]);
        acc[j] = fmaf(wc[j], cw[j].z, acc[j]);
        acc[j] = fmaf(wd[j], cw[j].w, acc[j]);
      }
      uint4 o;
      o.x = (unsigned)f2bf(acc[0]) | ((unsigned)f2bf(acc[1]) << 16);
      o.y = (unsigned)f2bf(acc[2]) | ((unsigned)f2bf(acc[3]) << 16);
      o.z = (unsigned)f2bf(acc[4]) | ((unsigned)f2bf(acc[5]) << 16);
      o.w = (unsigned)f2bf(acc[6]) | ((unsigned)f2bf(acc[7]) << 16);
      *(uint4*)(outp + (size_t)i * DIM) = o;
    }
#pragma unroll
    for (int j = 0; j < 8; ++j) { wa[j] = wb[j]; wb[j] = wc[j]; wc[j] = wd[j]; }
  }
}

#define GAS(p) ((const __attribute__((address_space(1))) void*)(p))
#define LAS(p) ((__attribute__((address_space(3))) void*)(p))

// ---------------- 128x128 BK=64 GEMM (r10 known-good): 2-barrier, 0 conflicts ----------
// LDS [128][64] bf16, XOR-swizzled 16B blocks: phys = log ^ (row&7), both sides (rule #21).
// XCD-banded main; TAIL=1 appends extra bm row-tiles in the SAME launch.
// SPLITK=1 (MODE 1): gid = bm*8+ks; each block does K/8; partials -> part[ks][r][48].
template <int MODE, int NBM, int NBN, int LX, int TAIL, int SPLITK>
__global__ __launch_bounds__(256) void gemm_bt(const unsigned short* __restrict__ A,
                                               const unsigned short* __restrict__ Bw,
                                               const float* __restrict__ bias,
                                               void* __restrict__ Cout, int K) {
  const int gid = blockIdx.x;
  const int mainBlocks = 8 * LX * NBN;
  int bm, bn, ks = 0;
  if constexpr (SPLITK) {
    ks = gid & 7;
    bm = gid >> 3;
    bn = 0;
  } else if (TAIL && gid >= mainBlocks) {
    const int e = gid - mainBlocks;
    bm = 8 * LX + e / NBN;
    bn = e % NBN;
  } else {
    const int xcd = gid & 7;
    const int j = gid >> 3;
    bm = xcd * LX + (j % LX);
    bn = j / LX;
  }
  if (bm >= NBM) return;

  __shared__ __align__(16) unsigned short As[128 * 64];   // 16KB
  __shared__ __align__(16) unsigned short Bs[128 * 64];   // 16KB
  const int tid = threadIdx.x;
  const int lane = tid & 63, wave = tid >> 6;
  const int wr = wave >> 1, wc = wave & 1;

  floatx4 acc[4][4];
#pragma unroll
  for (int i = 0; i < 4; ++i)
#pragma unroll
    for (int j2 = 0; j2 < 4; ++j2) acc[i][j2] = (floatx4){0.f, 0.f, 0.f, 0.f};

  const int srow = tid >> 3;
  const int scol = ((tid & 7) ^ ((tid >> 3) & 7)) * 8;
  const unsigned short* Ab[4];
  const unsigned short* Bb[4];
#pragma unroll
  for (int L = 0; L < 4; ++L) {
    Ab[L] = A  + (size_t)(bm * 128 + L * 32 + srow) * K + scol;
    Bb[L] = Bw + (size_t)(bn * 128 + L * 32 + srow) * K + scol;
  }

  const int fr = lane & 15;
  const int hi = lane >> 4;
  const int fx = fr & 7;

  const int kbase = SPLITK ? ks * (K >> 3) : 0;
  const int kend = kbase + (SPLITK ? (K >> 3) : K);

  for (int k0 = kbase; k0 < kend; k0 += 64) {
    __syncthreads();  // previous compute done before overwrite
#pragma unroll
    for (int L = 0; L < 4; ++L) {
      __builtin_amdgcn_global_load_lds(GAS(Ab[L] + k0), LAS(As + L * 2048 + tid * 8), 16, 0, 0);
      __builtin_amdgcn_global_load_lds(GAS(Bb[L] + k0), LAS(Bs + L * 2048 + tid * 8), 16, 0, 0);
    }
    __syncthreads();  // drains vmcnt -> LDS ready

#pragma unroll
    for (int kk = 0; kk < 2; ++kk) {
      const int pb = ((kk * 4 + hi) ^ fx) * 8;
      short8 af[4], bf[4];
#pragma unroll
      for (int mt = 0; mt < 4; ++mt) af[mt] = *(const short8*)&As[(wr * 64 + mt * 16 + fr) * 64 + pb];
#pragma unroll
      for (int nt = 0; nt < 4; ++nt) bf[nt] = *(const short8*)&Bs[(wc * 64 + nt * 16 + fr) * 64 + pb];
#pragma unroll
      for (int mt = 0; mt < 4; ++mt)
#pragma unroll
        for (int nt = 0; nt < 4; ++nt)
          acc[mt][nt] = __builtin_amdgcn_mfma_f32_16x16x32_bf16(af[mt], bf[nt], acc[mt][nt], 0, 0, 0);
    }
  }

  const int er = (lane >> 4) * 4, ec = lane & 15;
#pragma unroll
  for (int mt = 0; mt < 4; ++mt) {
#pragma unroll
    for (int nt = 0; nt < 4; ++nt) {
#pragma unroll
      for (int i = 0; i < 4; ++i) {
        int r = bm * 128 + wr * 64 + mt * 16 + er + i;
        int c = bn * 128 + wc * 64 + nt * 16 + ec;
        float v = acc[mt][nt][i];
        if constexpr (MODE == 0) {
          int bb = r >> 11, t = r & 2047;
          ((unsigned short*)Cout)[((size_t)bb * LPAD + 3 + t) * DIM + c] = f2bf(v + bias[c]);
        } else if constexpr (MODE == 1) {
          if (c < 48) ((float*)Cout)[((size_t)ks * M2P + r) * 48 + c] = v;
        } else {
          if (r < M2) ((float*)Cout)[(size_t)r * DMODEL + c] = v + bias[c];
        }
      }
    }
  }
}

// ---------------- 256x128 BK=64 GEMM (2-barrier template, bigger tile) ----------------
// Used for gemm<0> only (K=1024, NBM=64 exact): r17 showed it helps the short-K GEMM.
template <int MODE, int NBM, int NBN, int LX, int TAIL>
__global__ __launch_bounds__(512, 2) void gemm_big(const unsigned short* __restrict__ A,
                                                   const unsigned short* __restrict__ Bw,
                                                   const float* __restrict__ bias,
                                                   void* __restrict__ Cout, int K) {
  const int gid = blockIdx.x;
  const int mainBlocks = 8 * LX * NBN;
  int bm, bn;
  if (TAIL && gid >= mainBlocks) {
    const int e = gid - mainBlocks;
    bm = 8 * LX + e / NBN;
    bn = e % NBN;
  } else {
    const int xcd = gid & 7;
    const int j = gid >> 3;
    bm = xcd * LX + (j % LX);
    bn = j / LX;
  }
  if (bm >= NBM) return;

  __shared__ __align__(16) unsigned short As[256 * 64];   // 32KB
  __shared__ __align__(16) unsigned short Bs[128 * 64];   // 16KB
  const int tid = threadIdx.x;
  const int lane = tid & 63, wave = tid >> 6;   // wave 0..7
  const int wr = wave >> 1;                     // M quarter (64 rows)
  const int wc = wave & 1;                      // N half (64 cols)

  floatx4 acc[4][4];
#pragma unroll
  for (int i = 0; i < 4; ++i)
#pragma unroll
    for (int j2 = 0; j2 < 4; ++j2) acc[i][j2] = (floatx4){0.f, 0.f, 0.f, 0.f};

  const int srow = tid >> 3;                        // 0..63
  const int scol = ((tid & 7) ^ ((tid >> 3) & 7)) * 8;
  const unsigned short* Ab[4];
  const unsigned short* Bb[2];
#pragma unroll
  for (int L = 0; L < 4; ++L)
    Ab[L] = A  + (size_t)(bm * 256 + L * 64 + srow) * K + scol;
#pragma unroll
  for (int L = 0; L < 2; ++L)
    Bb[L] = Bw + (size_t)(bn * 128 + L * 64 + srow) * K + scol;

  const int fr = lane & 15;
  const int hi = lane >> 4;
  const int fx = fr & 7;

  for (int k0 = 0; k0 < K; k0 += 64) {
    __syncthreads();
#pragma unroll
    for (int L = 0; L < 4; ++L)
      __builtin_amdgcn_global_load_lds(GAS(Ab[L] + k0), LAS(As + L * 4096 + tid * 8), 16, 0, 0);
#pragma unroll
    for (int L = 0; L < 2; ++L)
      __builtin_amdgcn_global_load_lds(GAS(Bb[L] + k0), LAS(Bs + L * 4096 + tid * 8), 16, 0, 0);
    __syncthreads();

#pragma unroll
    for (int kk = 0; kk < 2; ++kk) {
      const int pb = ((kk * 4 + hi) ^ fx) * 8;
      short8 af[4], bf[4];
#pragma unroll
      for (int mt = 0; mt < 4; ++mt) af[mt] = *(const short8*)&As[(wr * 64 + mt * 16 + fr) * 64 + pb];
#pragma unroll
      for (int nt = 0; nt < 4; ++nt) bf[nt] = *(const short8*)&Bs[(wc * 64 + nt * 16 + fr) * 64 + pb];
#pragma unroll
      for (int mt = 0; mt < 4; ++mt)
#pragma unroll
        for (int nt = 0; nt < 4; ++nt)
          acc[mt][nt] = __builtin_amdgcn_mfma_f32_16x16x32_bf16(af[mt], bf[nt], acc[mt][nt], 0, 0, 0);
    }
  }

  const int er = (lane >> 4) * 4, ec = lane & 15;
#pragma unroll
  for (int mt = 0; mt < 4; ++mt) {
#pragma unroll
    for (int nt = 0; nt < 4; ++nt) {
#pragma unroll
      for (int i = 0; i < 4; ++i) {
        int r = bm * 256 + wr * 64 + mt * 16 + er + i;
        int c = bn * 128 + wc * 64 + nt * 16 + ec;
        float v = acc[mt][nt][i];
        if constexpr (MODE == 0) {
          int bb = r >> 11, t = r & 2047;
          ((unsigned short*)Cout)[((size_t)bb * LPAD + 3 + t) * DIM + c] = f2bf(v + bias[c]);
        } else {
          if (r < M2) ((float*)Cout)[(size_t)r * DMODEL + c] = v + bias[c];
        }
      }
    }
  }
}

// ---------------- reduce split-K partials -> xdbl (deterministic, no atomics) ----------
__global__ __launch_bounds__(256) void reduce_xdbl(const float* __restrict__ part,
                                                   float* __restrict__ xdbl) {
  int i = blockIdx.x * 256 + threadIdx.x;     // float4 index over [M2][48]
  if (i >= 196896) return;                    // 16408*48/4
  float4 s = make_float4(0.f, 0.f, 0.f, 0.f);
#pragma unroll
  for (int ks = 0; ks < 8; ++ks) {
    float4 v = *(const float4*)(part + (size_t)ks * M2P * 48 + (size_t)i * 4);
    s.x += v.x; s.y += v.y; s.z += v.z; s.w += v.w;
  }
  *(float4*)(xdbl + (size_t)i * 4) = s;
}

// ---------------- delta precompute: softplus(d_raw @ W_dt.T + b_dt) -> bf16 ----------------
__global__ __launch_bounds__(256) void delta_kernel(const float* __restrict__ xdbl,
                                                    const float* __restrict__ W_dt,
                                                    const float* __restrict__ b_dt,
                                                    unsigned short* __restrict__ delta) {
  const int d = blockIdx.y * 256 + threadIdx.x;
  const int r0 = blockIdx.x * 8;
  float wv[16];
  const float4* wp = (const float4*)(W_dt + (size_t)d * 16);
#pragma unroll
  for (int q = 0; q < 4; ++q) {
    float4 t = wp[q];
    wv[q * 4 + 0] = t.x; wv[q * 4 + 1] = t.y; wv[q * 4 + 2] = t.z; wv[q * 4 + 3] = t.w;
  }
  const float bd = b_dt[d];
#pragma unroll
  for (int j = 0; j < 8; ++j) {
    const float* dr = xdbl + (size_t)(r0 + j) * 48;   // uniform -> s_load
    float z0 = bd, z1 = 0.f, z2 = 0.f, z3 = 0.f;
#pragma unroll
    for (int n = 0; n < 16; n += 4) {
      z0 = fmaf(dr[n + 0], wv[n + 0], z0);
      z1 = fmaf(dr[n + 1], wv[n + 1], z1);
      z2 = fmaf(dr[n + 2], wv[n + 2], z2);
      z3 = fmaf(dr[n + 3], wv[n + 3], z3);
    }
    float z = (z0 + z1) + (z2 + z3);
    float dl = (z > 20.f) ? z : __logf(1.f + __expf(z));
    delta[(size_t)(r0 + j) * DIM + d] = f2bf(dl);
  }
}

// ---------------- chunked scan, pass 1: per-chunk (sumd, q) -> bf16 ----------------
__global__ __launch_bounds__(256, 4) void scan_pass1(const unsigned short* __restrict__ xc,
                                                     const unsigned short* __restrict__ dl,
                                                     const float* __restrict__ xd,
                                                     unsigned short* __restrict__ sdbuf,
                                                     unsigned short* __restrict__ qbuf) {
  const int wid = __builtin_amdgcn_readfirstlane((int)(threadIdx.x >> 6));
  const int lane = threadIdx.x & 63;
  const int W = blockIdx.x * 4 + wid;
  const int dg = W & 31;
  const int rest = W >> 5;
  const int c = rest % NCH;
  const int b = rest / NCH;
  const int d = dg * 64 + lane;
  const int t0 = c * CS;
  const int nst = (t0 + CS <= LC) ? CS : (LC - t0);

  float2v A2L[8];
#pragma unroll
  for (int i = 0; i < 8; ++i)
    A2L[i] = (float2v){AeT[2 * i] * LOG2E, AeT[2 * i + 1] * LOG2E};

  float2v h2[8];
#pragma unroll
  for (int i = 0; i < 8; ++i) h2[i] = (float2v){0.f, 0.f};
  float sumd = 0.f;

  const size_t row0 = (size_t)b * LC + t0;
  const float* xdb = xd + row0 * 48 + 16;            // B cols (uniform -> s_load)
  const unsigned short* xcp = xc + row0 * DIM + d;
  const unsigned short* dp  = dl + row0 * DIM + d;

  auto body = [&](int s) {
    float2v Bv[8];
#pragma unroll
    for (int j = 0; j < 8; ++j) Bv[j] = *(const float2v*)(xdb + (size_t)s * 48 + 2 * j);
    float dlt = bf2f(dp[(size_t)s * DIM]);
    float xcv = bf2f(xcp[(size_t)s * DIM]);
    sumd += dlt;
    float2v dlt2 = (float2v){dlt, dlt};
    float2v xcv2 = (float2v){xcv, xcv};
#pragma unroll
    for (int i = 0; i < 8; ++i) {
      float2v arg = pk_mul_vv(dlt2, A2L[i]);
      float e0 = exp2_raw(arg.x), e1 = exp2_raw(arg.y);
      float2v e2 = (float2v){e0, e1};
      h2[i] = pk_fma_vvv(h2[i], e2, pk_mul_sv(Bv[i], xcv2));
    }
  };

  if (nst == CS) {
#pragma unroll
    for (int s = 0; s < CS; ++s) body(s);
  } else {
    for (int s = 0; s < nst; ++s) body(s);
  }

  sdbuf[((size_t)(b * NCH + c) << 11) + d] = f2bf(sumd);
  const size_t base = ((size_t)(b * NCH + c) * 16) * 2048 + d;
#pragma unroll
  for (int i = 0; i < 8; ++i) {
    qbuf[base + ((size_t)(2 * i) << 11)]     = f2bf(h2[i].x);
    qbuf[base + ((size_t)(2 * i + 1) << 11)] = f2bf(h2[i].y);
  }
}

// ---------------- boundary scan: 1 lane per (b,d,n); h across chunks, h_init over q ----
__global__ __launch_bounds__(256) void scan_boundary(const unsigned short* __restrict__ sdbuf,
                                                     unsigned short* __restrict__ qbuf) {
  const int tid = threadIdx.x;
  const int n = tid >> 4;
  const int d = blockIdx.x * 16 + (tid & 15);
  const int b = blockIdx.y;
  const float aL = AeT[n] * LOG2E;
  float h = 0.f;
  for (int c = 0; c < NCH; ++c) {
    const size_t sbase = ((size_t)(b * NCH + c) << 11);
    const float sd = bf2f(sdbuf[sbase + d]);
    const size_t base = (sbase << 4) + ((size_t)n << 11) + d;
    const float qv = bf2f(qbuf[base]);
    const float Pv = exp2_raw(sd * aL);
    qbuf[base] = f2bf(h);
    h = fmaf(Pv, h, qv);
  }
}

// ---------------- chunked scan, pass 2: recompute with h_init, emit y ----------------
// NOTE: y aliases dl (in-place, same [r][d] layout); only the owning thread touches
// each element and reads precede the store for that row.
__global__ __launch_bounds__(256, 4) void scan_pass2(const unsigned short* __restrict__ xc,
                                                     const unsigned short* __restrict__ dl,
                                                     const float* __restrict__ xd,
                                                     const unsigned short* __restrict__ hinit,
                                                     unsigned short* __restrict__ y) {
  const int wid = __builtin_amdgcn_readfirstlane((int)(threadIdx.x >> 6));
  const int lane = threadIdx.x & 63;
  const int W = blockIdx.x * 4 + wid;
  const int dg = W & 31;
  const int rest = W >> 5;
  const int c = rest % NCH;
  const int b = rest / NCH;
  const int d = dg * 64 + lane;
  const int t0 = c * CS;
  const int nst = (t0 + CS <= LC) ? CS : (LC - t0);

  float2v A2L[8];
#pragma unroll
  for (int i = 0; i < 8; ++i)
    A2L[i] = (float2v){AeT[2 * i] * LOG2E, AeT[2 * i + 1] * LOG2E};

  const size_t base = ((size_t)(b * NCH + c) * 16) * 2048 + d;
  float2v h2[8];
#pragma unroll
  for (int i = 0; i < 8; ++i)
    h2[i] = (float2v){bf2f(hinit[base + ((size_t)(2 * i) << 11)]),
                      bf2f(hinit[base + ((size_t)(2 * i + 1) << 11)])};

  const size_t row0 = (size_t)b * LC + t0;
  const float* xdb = xd + row0 * 48 + 16;            // B at [j], C at [16+j]
  const unsigned short* xcp = xc + row0 * DIM + d;
  const unsigned short* dp  = dl + row0 * DIM + d;
  unsigned short* yp = y + row0 * DIM + d;

  auto body = [&](int s) {
    float2v Bv[8], Cv[8];
#pragma unroll
    for (int j = 0; j < 8; ++j) {
      Bv[j] = *(const float2v*)(xdb + (size_t)s * 48 + 2 * j);
      Cv[j] = *(const float2v*)(xdb + (size_t)s * 48 + 16 + 2 * j);
    }
    float dlt = bf2f(dp[(size_t)s * DIM]);
    float xcv = bf2f(xcp[(size_t)s * DIM]);
    float2v dlt2 = (float2v){dlt, dlt};
    float2v xcv2 = (float2v){xcv, xcv};
    float2v y2[4];
#pragma unroll
    for (int i = 0; i < 4; ++i) y2[i] = (float2v){0.f, 0.f};
#pragma unroll
    for (int i = 0; i < 8; ++i) {
      float2v arg = pk_mul_vv(dlt2, A2L[i]);
      float e0 = exp2_raw(arg.x), e1 = exp2_raw(arg.y);
      float2v e2 = (float2v){e0, e1};
      h2[i] = pk_fma_vvv(h2[i], e2, pk_mul_sv(Bv[i], xcv2));
      y2[i & 3] = pk_fma_vsv(h2[i], Cv[i], y2[i & 3]);
    }
    float2v s01 = pk_add_vv(y2[0], y2[1]);
    float2v s23 = pk_add_vv(y2[2], y2[3]);
    float2v st = pk_add_vv(s01, s23);
    yp[(size_t)s * DIM] = f2bf(st.x + st.y);
  };

  if (nst == CS) {
#pragma unroll
    for (int s = 0; s < CS; ++s) body(s);
  } else {
    for (int s = 0; s < nst; ++s) body(s);
  }
}

// ---------------- launch ----------------
extern "C" void kernel_launch(void* const* d_in, const int* in_sizes, int n_in,
                              void* d_out, int out_size, void* d_ws, size_t ws_size,
                              hipStream_t stream) {
  const float* x      = (const float*)d_in[0];
  const float* W_in   = (const float*)d_in[1];
  const float* b_in   = (const float*)d_in[2];
  const float* conv_w = (const float*)d_in[3];
  const float* conv_b = (const float*)d_in[4];
  const float* W_x    = (const float*)d_in[5];
  const float* W_dt   = (const float*)d_in[6];
  const float* b_dt   = (const float*)d_in[7];
  const float* W_out  = (const float*)d_in[8];
  const float* b_out  = (const float*)d_in[9];

  char* w = (char*)d_ws;
  // region 0 (67.63 MB): xp (LPAD layout) -> delta [M2P][DIM] -> y (in-place over delta)
  unsigned short* xp    = (unsigned short*)w;
  unsigned short* delta = (unsigned short*)w;
  unsigned short* ybuf  = (unsigned short*)w;
  size_t off = (size_t)M2P * DIM * 2;                                  // 67,633,152
  unsigned short* xcb  = (unsigned short*)(w + off); off += (size_t)M2P * DIM * 2;
  size_t xA_off = off;                                                 // 135,266,304
  unsigned short* xA   = (unsigned short*)(w + off); off += (size_t)16384 * 1024 * 2;
  unsigned short* wInB = (unsigned short*)(w + off); off += (size_t)2048 * 1024 * 2;
  unsigned short* wOutB= (unsigned short*)(w + off); off += (size_t)1024 * 2048 * 2;
  unsigned short* wXB  = (unsigned short*)(w + off); off += (size_t)128 * 2048 * 2;
  float* xdbl          = (float*)(w + off);          off += (size_t)M2 * 48 * 4;
  // xA region (37.5 MB, dead after gemm<0>) reused twice:
  //  1) split-K partials (8 * M2P * 48 * 4 = 25.4 MB) between gemm<1> and reduce
  //  2) sdbuf (2.13 MB) + qbuf (34.08 MB) bf16 from scan_pass1 onward
  float* part           = (float*)(w + xA_off);
  unsigned short* sdbuf = (unsigned short*)(w + xA_off);
  unsigned short* qbuf  = (unsigned short*)(w + xA_off + (size_t)B8 * NCH * 2048 * 2);
  (void)ws_size; (void)in_sizes; (void)n_in; (void)out_size;

  init_kernel<<<10336, 256, 0, stream>>>(x, W_in, W_out, W_x, xA, wInB, wOutB, wXB, xp);

  // gemm<0>: 256x128 tiles (best for K=1024), NBM=64 exact (LX=8), NBN=16 -> grid 1024
  gemm_big<0, 64, 16, 8, 0><<<1024, 512, 0, stream>>>(xA, wInB, b_in, xp, 1024);
  conv_kernel<<<dim3(129, B8), 256, 0, stream>>>(xp, conv_w, conv_b, xcb);
  // gemm<1>: split-K=8 on 128-tile kernel, then deterministic reduce
  gemm_bt<1, 129, 1, 0, 0, 1><<<1032, 256, 0, stream>>>(xcb, wXB, nullptr, part, 2048);
  reduce_xdbl<<<770, 256, 0, stream>>>(part, xdbl);
  delta_kernel<<<dim3(2051, 8), 256, 0, stream>>>(xdbl, W_dt, b_dt, delta);

  scan_pass1<<<4160, 256, 0, stream>>>(xcb, delta, xdbl, sdbuf, qbuf);
  scan_boundary<<<dim3(128, B8), 256, 0, stream>>>(sdbuf, qbuf);
  scan_pass2<<<4160, 256, 0, stream>>>(xcb, delta, xdbl, qbuf, ybuf);

  // gemm<2>: 128x128 tiles (best for K=2048): banded 1024 + 8 integrated tail blocks
  gemm_bt<2, 129, 8, 16, 1, 0><<<1032, 256, 0, stream>>>(ybuf, wOutB, b_out, (float*)d_out, 2048);
}